// Round 10
// baseline (493.664 us; speedup 1.0000x reference)
//
#include <hip/hip_runtime.h>
#include <hip/hip_bf16.h>
#include <hip/hip_cooperative_groups.h>

namespace cg = cooperative_groups;

#define NNODES 50000
#define NEDGES 640000
#define NGRAPH 64
#define HD     128
#define NPART  8
#define PRANGE (NNODES / NPART)   // 6250 (dst-range partition for CSR build)

typedef __attribute__((ext_vector_type(8))) short short8;
typedef __attribute__((ext_vector_type(4))) float f32x4;

__device__ __forceinline__ float uf(uint u) { return __uint_as_float(u); }
// fp32 -> bf16 round-to-nearest-even
__device__ __forceinline__ ushort f2b(float f) {
    uint u = __float_as_uint(f);
    return (ushort)((u + 0x7fffu + ((u >> 16) & 1u)) >> 16);
}

// ---------------------------------------------------------------------------
// wpinit: pack 5 fp32 128x128 weights into bf16 MFMA B-fragment order,
// AND zero count[] + pooled[].
// ---------------------------------------------------------------------------
__global__ __launch_bounds__(256) void wpinit_k(const float* __restrict__ W0,
                                                const float* __restrict__ W1,
                                                const float* __restrict__ W2,
                                                const float* __restrict__ W3,
                                                const float* __restrict__ W4,
                                                ushort* __restrict__ Wp,
                                                int* __restrict__ count,
                                                float* __restrict__ pooled) {
    int which = blockIdx.y;
    const float* W = (which == 0) ? W0 : (which == 1) ? W1 : (which == 2) ? W2
                   : (which == 3) ? W3 : W4;
    ushort* dst = Wp + (size_t)which * 16384;
    int idx = blockIdx.x * 256 + threadIdx.x;   // 0..2047
    int l  = idx & 63;
    int kt = (idx >> 6) & 3;
    int nt = idx >> 8;
    int krow = kt * 32 + (l >> 4) * 8;
    int col  = nt * 16 + (l & 15);
    short8 v;
#pragma unroll
    for (int j = 0; j < 8; ++j) v[j] = (short)f2b(W[(size_t)(krow + j) * HD + col]);
    *(short8*)(dst + ((size_t)(nt * 4 + kt) * 64 + l) * 8) = v;
    int fid = (blockIdx.y * 8 + blockIdx.x) * 256 + threadIdx.x;
    for (int i = fid; i < NNODES; i += 10240) count[i] = 0;
    for (int i = fid; i < NGRAPH * 384; i += 10240) pooled[i] = 0.f;
}

// ---------------------------------------------------------------------------
// Fused CSR build (ONE cooperative kernel): hist -> scan -> scatter.
// dst-range partitioned (p = bid&7 -> XCD-local atomics, round-8 win).
// 1024 blocks x 256 = 4 blocks/CU -> trivially co-resident.
// ---------------------------------------------------------------------------
__global__ __launch_bounds__(256) void csr_k(const int* __restrict__ src,
                                             const int* __restrict__ dst,
                                             int* __restrict__ count,
                                             int* __restrict__ blocksum,
                                             int* __restrict__ row_start,
                                             int* __restrict__ cur,
                                             ushort* __restrict__ nbr,
                                             int N, int E) {
    cg::grid_group grid = cg::this_grid();
    __shared__ int s[256];
    const int t = threadIdx.x;
    const int bid = blockIdx.x;
    const int nB = (N + 255) / 256;             // 196
    // phase 1: histogram (partitioned atomics)
    {
        int p = bid & 7, q = bid >> 3;          // q in 0..127
        int lo = p * PRANGE, hi = lo + PRANGE;
        for (int e = q * 256 + t; e < E; e += 128 * 256) {
            int d = dst[e];
            if (d >= lo && d < hi) atomicAdd(&count[d], 1);
        }
    }
    grid.sync();
    // phase 2a: per-block inclusive scan (blocks 0..nB-1), keep in registers
    int myv = 0, incl = 0;
    if (bid < nB) {
        int i = bid * 256 + t;
        myv = (i < N) ? count[i] : 0;
        s[t] = myv;
        __syncthreads();
        for (int off = 1; off < 256; off <<= 1) {
            int nv = s[t];
            if (t >= off) nv += s[t - off];
            __syncthreads();
            s[t] = nv;
            __syncthreads();
        }
        incl = s[t];
        if (t == 255) blocksum[bid] = s[255];
    }
    grid.sync();
    // phase 2b: every active block re-scans blocksums, finalizes its rows
    if (bid < nB) {
        s[t] = (t < nB) ? blocksum[t] : 0;
        __syncthreads();
        for (int off = 1; off < 256; off <<= 1) {
            int nv = s[t];
            if (t >= off) nv += s[t - off];
            __syncthreads();
            s[t] = nv;
            __syncthreads();
        }
        int boff = (bid == 0) ? 0 : s[bid - 1];
        int i = bid * 256 + t;
        if (i < N) {
            int excl = incl - myv + boff;
            row_start[i] = excl;
            cur[i] = excl;
        }
        if (i == N) row_start[N] = E;
    }
    grid.sync();
    // phase 3: scatter (partitioned atomics + XCD-local nbr writes)
    {
        int p = bid & 7, q = bid >> 3;
        int lo = p * PRANGE, hi = lo + PRANGE;
        for (int e = q * 256 + t; e < E; e += 128 * 256) {
            int d = dst[e];
            if (d >= lo && d < hi) {
                int pos = atomicAdd(&cur[d], 1);
                nbr[pos] = (ushort)src[e];
            }
        }
    }
}

// ---------------------------------------------------------------------------
// bf16 aggregation (row-major h, round-8 version): out[n] = h[n] + sum h[s].
// 2 nodes per wave; neighbor walk unrolled x8.
// ---------------------------------------------------------------------------
__global__ __launch_bounds__(256) void aggb_k(const ushort* __restrict__ h,
                                              const int* __restrict__ row_start,
                                              const ushort* __restrict__ nbr,
                                              ushort* __restrict__ out, int nNodes) {
    int gw   = (blockIdx.x * 256 + threadIdx.x) >> 6;
    int lane = threadIdx.x & 63;
    int node = gw * 2 + (lane >> 5);
    int sub  = lane & 31;
    if (node >= nNodes) return;
    const uint2* hp = (const uint2*)h;
    uint2 u = hp[(size_t)node * 32 + sub];
    float f0 = uf(u.x << 16), f1 = uf(u.x & 0xffff0000u);
    float f2v = uf(u.y << 16), f3 = uf(u.y & 0xffff0000u);
    int rs = row_start[node], re = row_start[node + 1];
    int p = rs;
#define ACC4(vv) { f0 += uf(vv.x << 16); f1 += uf(vv.x & 0xffff0000u); \
                   f2v += uf(vv.y << 16); f3 += uf(vv.y & 0xffff0000u); }
    for (; p + 8 <= re; p += 8) {
        int s0 = nbr[p],     s1 = nbr[p + 1], s2 = nbr[p + 2], s3 = nbr[p + 3];
        int s4 = nbr[p + 4], s5 = nbr[p + 5], s6 = nbr[p + 6], s7 = nbr[p + 7];
        uint2 v0 = hp[(size_t)s0 * 32 + sub];
        uint2 v1 = hp[(size_t)s1 * 32 + sub];
        uint2 v2 = hp[(size_t)s2 * 32 + sub];
        uint2 v3 = hp[(size_t)s3 * 32 + sub];
        uint2 v4 = hp[(size_t)s4 * 32 + sub];
        uint2 v5 = hp[(size_t)s5 * 32 + sub];
        uint2 v6 = hp[(size_t)s6 * 32 + sub];
        uint2 v7 = hp[(size_t)s7 * 32 + sub];
        ACC4(v0) ACC4(v1) ACC4(v2) ACC4(v3)
        ACC4(v4) ACC4(v5) ACC4(v6) ACC4(v7)
    }
    for (; p + 4 <= re; p += 4) {
        int s0 = nbr[p], s1 = nbr[p + 1], s2 = nbr[p + 2], s3 = nbr[p + 3];
        uint2 v0 = hp[(size_t)s0 * 32 + sub];
        uint2 v1 = hp[(size_t)s1 * 32 + sub];
        uint2 v2 = hp[(size_t)s2 * 32 + sub];
        uint2 v3 = hp[(size_t)s3 * 32 + sub];
        ACC4(v0) ACC4(v1) ACC4(v2) ACC4(v3)
    }
    for (; p < re; ++p) {
        int s = nbr[p];
        uint2 v = hp[(size_t)s * 32 + sub];
        ACC4(v)
    }
#undef ACC4
    uint2 o;
    o.x = (uint)f2b(f0) | ((uint)f2b(f1) << 16);
    o.y = (uint)f2b(f2v) | ((uint)f2b(f3) << 16);
    ((uint2*)out)[(size_t)node * 32 + sub] = o;
}

// ---------------------------------------------------------------------------
// 128x128 bf16 MFMA GEMM step on an LDS tile (in-place safe per wave).
// ---------------------------------------------------------------------------
__device__ __forceinline__ void gemm128(const ushort* __restrict__ A,
                                        const short8* __restrict__ Wp,
                                        const float* __restrict__ bias,
                                        ushort* __restrict__ D, int tid) {
    const int l = tid & 63, w = tid >> 6;
    const int lr = l & 15, lg = l >> 4;
    const int wbase = w * 32;
    const int sw = lr & 7;
    f32x4 acc[2][8];
    const f32x4 z4 = {0.f, 0.f, 0.f, 0.f};
#pragma unroll
    for (int m = 0; m < 2; ++m)
#pragma unroll
        for (int n = 0; n < 8; ++n) acc[m][n] = z4;
#pragma unroll
    for (int kt = 0; kt < 4; ++kt) {
        const int pch = ((kt * 4 + lg) ^ sw) * 8;
        short8 a0 = *(const short8*)(A + (wbase + lr) * 128 + pch);
        short8 a1 = *(const short8*)(A + (wbase + 16 + lr) * 128 + pch);
#pragma unroll
        for (int n = 0; n < 8; ++n) {
            short8 b = Wp[(n * 4 + kt) * 64 + l];
            acc[0][n] = __builtin_amdgcn_mfma_f32_16x16x32_bf16(a0, b, acc[0][n], 0, 0, 0);
            acc[1][n] = __builtin_amdgcn_mfma_f32_16x16x32_bf16(a1, b, acc[1][n], 0, 0, 0);
        }
    }
#pragma unroll
    for (int n = 0; n < 8; ++n) {
        const int col = n * 16 + lr;
        const float bb = bias[col];
        const int cch = col >> 3, cof = col & 7;
#pragma unroll
        for (int m = 0; m < 2; ++m) {
#pragma unroll
            for (int r = 0; r < 4; ++r) {
                int row = wbase + m * 16 + lg * 4 + r;
                float t = fmaxf(acc[m][n][r] + bb, 0.f);
                D[row * 128 + ((cch ^ (row & 7)) * 8) + cof] = f2b(t);
            }
        }
    }
}

// Segmented pool of the LDS tile into pooled[g*384 + coloff + col].
__device__ __forceinline__ void pool_tile(const ushort* __restrict__ T,
                                          const int* __restrict__ batchl,
                                          float* __restrict__ pooled,
                                          int coloff, int tid) {
    int col = tid & 127, half = tid >> 7;
    int cch = col >> 3, cof = col & 7;
    float pacc = 0.f;
    int curg = -1;
    for (int r = half * 64; r < half * 64 + 64; ++r) {
        int g = batchl[r];
        if (g != curg) {
            if (curg >= 0) atomicAdd(&pooled[curg * 384 + coloff + col], pacc);
            curg = g;
            pacc = 0.f;
        }
        if (g >= 0) pacc += uf((uint)T[r * 128 + ((cch ^ (r & 7)) * 8) + cof] << 16);
    }
    if (curg >= 0) atomicAdd(&pooled[curg * 384 + coloff + col], pacc);
}

// ---------------------------------------------------------------------------
// Fused layer 1: h1 = relu(relu((x + agg(x)) @ W1 + b1) @ W2 + b2) + pool
// ---------------------------------------------------------------------------
__global__ __launch_bounds__(256) void fl1_k(const float* __restrict__ x,
                                             const int* __restrict__ batch,
                                             const int* __restrict__ row_start,
                                             const ushort* __restrict__ nbr,
                                             const float* __restrict__ W1, // 8x128
                                             const float* __restrict__ b1,
                                             const short8* __restrict__ Wp2,
                                             const float* __restrict__ b2,
                                             ushort* __restrict__ out,
                                             float* __restrict__ pooled, int nNodes) {
    __shared__ float hin[128][8];
    __shared__ __align__(16) ushort T[128 * 128];
    __shared__ int batchl[128];
    int t = threadIdx.x;
    int n0 = blockIdx.x * 128;
    if (t < 128) batchl[t] = (n0 + t < nNodes) ? batch[n0 + t] : -1;
    {   // gather-sum staging: 2 threads per row, unroll x8
        int r = t >> 1;
        int half = t & 1;
        int n = n0 + r;
        float4 v = make_float4(0.f, 0.f, 0.f, 0.f);
        if (n < nNodes) {
            v = *(const float4*)(x + (size_t)n * 8 + half * 4);
            int rs = row_start[n], re = row_start[n + 1];
            int p = rs;
#define AX(u) { v.x += u.x; v.y += u.y; v.z += u.z; v.w += u.w; }
            for (; p + 8 <= re; p += 8) {
                int s0 = nbr[p],     s1 = nbr[p + 1], s2 = nbr[p + 2], s3 = nbr[p + 3];
                int s4 = nbr[p + 4], s5 = nbr[p + 5], s6 = nbr[p + 6], s7 = nbr[p + 7];
                float4 u0 = *(const float4*)(x + (size_t)s0 * 8 + half * 4);
                float4 u1 = *(const float4*)(x + (size_t)s1 * 8 + half * 4);
                float4 u2 = *(const float4*)(x + (size_t)s2 * 8 + half * 4);
                float4 u3 = *(const float4*)(x + (size_t)s3 * 8 + half * 4);
                float4 u4 = *(const float4*)(x + (size_t)s4 * 8 + half * 4);
                float4 u5 = *(const float4*)(x + (size_t)s5 * 8 + half * 4);
                float4 u6 = *(const float4*)(x + (size_t)s6 * 8 + half * 4);
                float4 u7 = *(const float4*)(x + (size_t)s7 * 8 + half * 4);
                AX(u0) AX(u1) AX(u2) AX(u3) AX(u4) AX(u5) AX(u6) AX(u7)
            }
            for (; p < re; ++p) {
                int s = nbr[p];
                float4 u = *(const float4*)(x + (size_t)s * 8 + half * 4);
                AX(u)
            }
#undef AX
        }
        *(float4*)(&hin[r][half * 4]) = v;
    }
    __syncthreads();
    // MLP1 (8->128), bf16 result into swizzled T
    int tx = t & 15, ty = t >> 4;
    float w[8][8];
#pragma unroll
    for (int k = 0; k < 8; ++k) {
        float4 w0 = *(const float4*)(W1 + k * HD + tx * 8);
        float4 w1 = *(const float4*)(W1 + k * HD + tx * 8 + 4);
        w[k][0] = w0.x; w[k][1] = w0.y; w[k][2] = w0.z; w[k][3] = w0.w;
        w[k][4] = w1.x; w[k][5] = w1.y; w[k][6] = w1.z; w[k][7] = w1.w;
    }
    float4 c0 = *(const float4*)(b1 + tx * 8);
    float4 c1 = *(const float4*)(b1 + tx * 8 + 4);
    float bb[8] = {c0.x, c0.y, c0.z, c0.w, c1.x, c1.y, c1.z, c1.w};
#pragma unroll
    for (int i = 0; i < 8; ++i) {
        int r = ty * 8 + i;
        float4 a0 = *(const float4*)(&hin[r][0]);
        float4 a1 = *(const float4*)(&hin[r][4]);
        float a[8] = {a0.x, a0.y, a0.z, a0.w, a1.x, a1.y, a1.z, a1.w};
        short8 ov;
#pragma unroll
        for (int jj = 0; jj < 8; ++jj) {
            float acc = bb[jj];
#pragma unroll
            for (int k = 0; k < 8; ++k) acc += a[k] * w[k][jj];
            ov[jj] = (short)f2b(fmaxf(acc, 0.f));
        }
        *(short8*)(T + r * 128 + ((tx ^ (r & 7)) * 8)) = ov;
    }
    __syncthreads();
    gemm128(T, Wp2, b2, T, t);
    __syncthreads();
#pragma unroll
    for (int i = 0; i < 8; ++i) {
        int idx = i * 256 + t;
        int row = idx >> 4, ch = idx & 15;
        int n = n0 + row;
        if (n < nNodes) {
            short8 v = *(const short8*)(T + row * 128 + ((ch ^ (row & 7)) * 8));
            *(short8*)(out + (size_t)n * HD + ch * 8) = v;
        }
    }
    pool_tile(T, batchl, pooled, 0, t);
}

// ---------------------------------------------------------------------------
// Fused layer MLP (layers 2,3): out = relu(relu(A@W1+b1)@W2+b2) + pool.
// STORE=0 skips the global h-store (layer 3).
// ---------------------------------------------------------------------------
template <int STORE>
__global__ __launch_bounds__(256) void fmm_k(const ushort* __restrict__ Ain,
                                             const int* __restrict__ batch,
                                             const short8* __restrict__ Wp1,
                                             const float* __restrict__ b1,
                                             const short8* __restrict__ Wp2,
                                             const float* __restrict__ b2,
                                             ushort* __restrict__ out,
                                             float* __restrict__ pooled,
                                             int coloff, int nNodes) {
    __shared__ __align__(16) ushort T[128 * 128];
    __shared__ int batchl[128];
    const int t = threadIdx.x;
    const int n0 = blockIdx.x * 128;
    if (t < 128) batchl[t] = (n0 + t < nNodes) ? batch[n0 + t] : -1;
#pragma unroll
    for (int i = 0; i < 8; ++i) {
        int idx = i * 256 + t;
        int row = idx >> 4, ch = idx & 15;
        short8 v = {0, 0, 0, 0, 0, 0, 0, 0};
        int n = n0 + row;
        if (n < nNodes) v = *(const short8*)(Ain + (size_t)n * HD + ch * 8);
        *(short8*)(T + row * 128 + ((ch ^ (row & 7)) * 8)) = v;
    }
    __syncthreads();
    gemm128(T, Wp1, b1, T, t);
    __syncthreads();
    gemm128(T, Wp2, b2, T, t);
    __syncthreads();
    if constexpr (STORE) {
#pragma unroll
        for (int i = 0; i < 8; ++i) {
            int idx = i * 256 + t;
            int row = idx >> 4, ch = idx & 15;
            int n = n0 + row;
            if (n < nNodes) {
                short8 v = *(const short8*)(T + row * 128 + ((ch ^ (row & 7)) * 8));
                *(short8*)(out + (size_t)n * HD + ch * 8) = v;
            }
        }
    }
    pool_tile(T, batchl, pooled, coloff, t);
}

// ---------------------------------------------------------------------------
// Classifier (all fp32)
// ---------------------------------------------------------------------------
__global__ __launch_bounds__(256) void cls_k(const float* __restrict__ pooled,
                                             const float* __restrict__ W1,  // 384x256
                                             const float* __restrict__ b1,
                                             const float* __restrict__ gamma,
                                             const float* __restrict__ beta,
                                             const float* __restrict__ mean,
                                             const float* __restrict__ var,
                                             const float* __restrict__ W2,  // 256x4
                                             const float* __restrict__ b2,
                                             float* __restrict__ out) {
    __shared__ float pg[384];
    __shared__ float z[256];
    int g = blockIdx.x, j = threadIdx.x;
    pg[j] = pooled[g * 384 + j];
    if (j < 128) pg[256 + j] = pooled[g * 384 + 256 + j];
    __syncthreads();
    float acc = b1[j];
    for (int k = 0; k < 384; ++k) acc += pg[k] * W1[k * 256 + j];
    acc = (acc - mean[j]) * rsqrtf(var[j] + 1e-5f) * gamma[j] + beta[j];
    z[j] = fmaxf(acc, 0.f);
    __syncthreads();
    if (j < 4) {
        float o = b2[j];
        for (int k = 0; k < 256; ++k) o += z[k] * W2[k * 4 + j];
        out[g * 4 + j] = o;
    }
}

// ---------------------------------------------------------------------------
extern "C" void kernel_launch(void* const* d_in, const int* in_sizes, int n_in,
                              void* d_out, int out_size, void* d_ws, size_t ws_size,
                              hipStream_t stream) {
    const int N = NNODES, E = NEDGES;
    const float* x     = (const float*)d_in[0];
    const int*   ei    = (const int*)d_in[1];
    const int*   batch = (const int*)d_in[2];
    const float* l1W1 = (const float*)d_in[3];
    const float* l1b1 = (const float*)d_in[4];
    const float* l1W2 = (const float*)d_in[5];
    const float* l1b2 = (const float*)d_in[6];
    const float* l2W1 = (const float*)d_in[7];
    const float* l2b1 = (const float*)d_in[8];
    const float* l2W2 = (const float*)d_in[9];
    const float* l2b2 = (const float*)d_in[10];
    const float* l3W1 = (const float*)d_in[11];
    const float* l3b1 = (const float*)d_in[12];
    const float* l3W2 = (const float*)d_in[13];
    const float* l3b2 = (const float*)d_in[14];
    const float* cW1  = (const float*)d_in[15];
    const float* cb1  = (const float*)d_in[16];
    const float* bnG  = (const float*)d_in[17];
    const float* bnB  = (const float*)d_in[18];
    const float* bnM  = (const float*)d_in[19];
    const float* bnV  = (const float*)d_in[20];
    const float* cW2  = (const float*)d_in[21];
    const float* cb2  = (const float*)d_in[22];

    const int* src = ei;
    const int* dst = ei + E;

    // ---- workspace layout ----
    char* wsp = (char*)d_ws;
    ushort* tmpb = (ushort*)wsp;  wsp += (size_t)N * HD * 2;   // row-major
    ushort* h1   = (ushort*)wsp;  wsp += (size_t)N * HD * 2;
    ushort* h2   = (ushort*)wsp;  wsp += (size_t)N * HD * 2;
    float* pooled = (float*)wsp;  wsp += (size_t)64 * 384 * 4;
    ushort* wp    = (ushort*)wsp; wsp += (size_t)5 * 16384 * 2;
    int* count    = (int*)wsp;    wsp += (size_t)N * 4;
    int* blocksum = (int*)wsp;    wsp += 256 * 4;
    int* row_start = (int*)wsp;   wsp += (size_t)(N + 1) * 4;
    int* cur       = (int*)wsp;   wsp += (size_t)N * 4;
    ushort* nbr    = (ushort*)wsp; wsp += (size_t)E * 2;

    // setup: weight pack + zero count/pooled
    wpinit_k<<<dim3(8, 5), 256, 0, stream>>>(l1W2, l2W1, l2W2, l3W1, l3W2,
                                             wp, count, pooled);
    // fused CSR build (cooperative: hist -> scan -> scatter)
    {
        int Nv = N, Ev = E;
        void* args[] = {(void*)&src, (void*)&dst, (void*)&count, (void*)&blocksum,
                        (void*)&row_start, (void*)&cur, (void*)&nbr,
                        (void*)&Nv, (void*)&Ev};
        hipLaunchCooperativeKernel((void*)csr_k, dim3(1024), dim3(256),
                                   args, 0, stream);
    }

    const short8* Wp0 = (const short8*)(wp);
    const short8* Wp1 = (const short8*)(wp + 16384);
    const short8* Wp2 = (const short8*)(wp + 2 * 16384);
    const short8* Wp3 = (const short8*)(wp + 3 * 16384);
    const short8* Wp4 = (const short8*)(wp + 4 * 16384);

    const int mb = (N + 127) / 128;              // 391 tiles
    const int ab = ((N + 1) / 2 * 64) / 256;     // 6250 blocks
    // layer 1 (gather + MLP1 + GEMM2 + pool fused)
    fl1_k<<<mb, 256, 0, stream>>>(x, batch, row_start, nbr, l1W1, l1b1, Wp0, l1b2,
                                  h1, pooled, N);
    // layer 2
    aggb_k<<<ab, 256, 0, stream>>>(h1, row_start, nbr, tmpb, N);
    fmm_k<1><<<mb, 256, 0, stream>>>(tmpb, batch, Wp1, l2b1, Wp2, l2b2, h2,
                                     pooled, 128, N);
    // layer 3 (no h3 store)
    aggb_k<<<ab, 256, 0, stream>>>(h2, row_start, nbr, tmpb, N);
    fmm_k<0><<<mb, 256, 0, stream>>>(tmpb, batch, Wp3, l3b1, Wp4, l3b2, nullptr,
                                     pooled, 256, N);
    // classifier
    cls_k<<<NGRAPH, 256, 0, stream>>>(pooled, cW1, cb1, bnG, bnB, bnM, bnV, cW2, cb2,
                                      (float*)d_out);
}

// Round 11
// 270.345 us; speedup vs baseline: 1.8260x; 1.8260x over previous
//
#include <hip/hip_runtime.h>
#include <hip/hip_bf16.h>

#define NNODES 50000
#define NEDGES 640000
#define NGRAPH 64
#define HD     128
#define NPART  8
#define PRANGE (NNODES / NPART)   // 6250 (dst-range partition for CSR build)

typedef __attribute__((ext_vector_type(8))) short short8;
typedef __attribute__((ext_vector_type(4))) float f32x4;

__device__ __forceinline__ float uf(uint u) { return __uint_as_float(u); }
// fp32 -> bf16 round-to-nearest-even
__device__ __forceinline__ ushort f2b(float f) {
    uint u = __float_as_uint(f);
    return (ushort)((u + 0x7fffu + ((u >> 16) & 1u)) >> 16);
}

// ---------------------------------------------------------------------------
// wpinit: pack 5 fp32 128x128 weights into bf16 MFMA B-fragment order,
// AND zero count[] + pooled[].
// ---------------------------------------------------------------------------
__global__ __launch_bounds__(256) void wpinit_k(const float* __restrict__ W0,
                                                const float* __restrict__ W1,
                                                const float* __restrict__ W2,
                                                const float* __restrict__ W3,
                                                const float* __restrict__ W4,
                                                ushort* __restrict__ Wp,
                                                int* __restrict__ count,
                                                float* __restrict__ pooled) {
    int which = blockIdx.y;
    const float* W = (which == 0) ? W0 : (which == 1) ? W1 : (which == 2) ? W2
                   : (which == 3) ? W3 : W4;
    ushort* dst = Wp + (size_t)which * 16384;
    int idx = blockIdx.x * 256 + threadIdx.x;   // 0..2047
    int l  = idx & 63;
    int kt = (idx >> 6) & 3;
    int nt = idx >> 8;
    int krow = kt * 32 + (l >> 4) * 8;
    int col  = nt * 16 + (l & 15);
    short8 v;
#pragma unroll
    for (int j = 0; j < 8; ++j) v[j] = (short)f2b(W[(size_t)(krow + j) * HD + col]);
    *(short8*)(dst + ((size_t)(nt * 4 + kt) * 64 + l) * 8) = v;
    int fid = (blockIdx.y * 8 + blockIdx.x) * 256 + threadIdx.x;
    for (int i = fid; i < NNODES; i += 10240) count[i] = 0;
    for (int i = fid; i < NGRAPH * 384; i += 10240) pooled[i] = 0.f;
}

// ---------------------------------------------------------------------------
// CSR build (round-8 structure: separate kernels, XCD dst-range partitioned)
// ---------------------------------------------------------------------------
__global__ __launch_bounds__(256) void phist_k(const int* __restrict__ dst,
                                               int* __restrict__ count, int E) {
    int p = blockIdx.x & 7;
    int q = blockIdx.x >> 3;
    int lo = p * PRANGE, hi = lo + PRANGE;
    for (int e = q * 256 + threadIdx.x; e < E; e += 256 * 256) {
        int d = dst[e];
        if (d >= lo && d < hi) atomicAdd(&count[d], 1);
    }
}

__global__ __launch_bounds__(256) void scan1_k(const int* __restrict__ count,
                                               int* __restrict__ row_tmp,
                                               int* __restrict__ blocksum, int N) {
    __shared__ int s[256];
    int t = threadIdx.x;
    int i = blockIdx.x * 256 + t;
    int v = (i < N) ? count[i] : 0;
    s[t] = v;
    __syncthreads();
    for (int off = 1; off < 256; off <<= 1) {
        int nv = s[t];
        if (t >= off) nv += s[t - off];
        __syncthreads();
        s[t] = nv;
        __syncthreads();
    }
    if (i < N) row_tmp[i] = s[t];
    if (t == 255) blocksum[blockIdx.x] = s[255];
}

__global__ __launch_bounds__(256) void scan23_k(const int* __restrict__ count,
                                                const int* __restrict__ row_tmp,
                                                const int* __restrict__ blocksum,
                                                int nB,
                                                int* __restrict__ row_start,
                                                int* __restrict__ cur, int N, int E) {
    __shared__ int s[256];
    int t = threadIdx.x;
    s[t] = (t < nB) ? blocksum[t] : 0;
    __syncthreads();
    for (int off = 1; off < 256; off <<= 1) {
        int nv = s[t];
        if (t >= off) nv += s[t - off];
        __syncthreads();
        s[t] = nv;
        __syncthreads();
    }
    int bid = blockIdx.x;
    int boff = (bid == 0) ? 0 : s[bid - 1];
    int i = bid * 256 + t;
    if (i < N) {
        int excl = row_tmp[i] - count[i] + boff;
        row_start[i] = excl;
        cur[i] = excl;
    }
    if (i == N) row_start[N] = E;
}

__global__ __launch_bounds__(256) void pscatter_k(const int* __restrict__ src,
                                                  const int* __restrict__ dst,
                                                  int* __restrict__ cur,
                                                  ushort* __restrict__ nbr, int E) {
    int p = blockIdx.x & 7;
    int q = blockIdx.x >> 3;
    int lo = p * PRANGE, hi = lo + PRANGE;
    for (int e = q * 256 + threadIdx.x; e < E; e += 256 * 256) {
        int d = dst[e];
        if (d >= lo && d < hi) {
            int pos = atomicAdd(&cur[d], 1);
            nbr[pos] = (ushort)src[e];
        }
    }
}

// ---------------------------------------------------------------------------
// 128x128 bf16 MFMA GEMM step on an LDS tile. Wave-private rows:
// wave w reads/writes only rows [32w, 32w+32). D = bf16(relu(A @ Wp + bias)).
// ---------------------------------------------------------------------------
__device__ __forceinline__ void gemm128(const ushort* __restrict__ A,
                                        const short8* __restrict__ Wp,
                                        const float* __restrict__ bias,
                                        ushort* __restrict__ D, int tid) {
    const int l = tid & 63, w = tid >> 6;
    const int lr = l & 15, lg = l >> 4;
    const int wbase = w * 32;
    const int sw = lr & 7;
    f32x4 acc[2][8];
    const f32x4 z4 = {0.f, 0.f, 0.f, 0.f};
#pragma unroll
    for (int m = 0; m < 2; ++m)
#pragma unroll
        for (int n = 0; n < 8; ++n) acc[m][n] = z4;
#pragma unroll
    for (int kt = 0; kt < 4; ++kt) {
        const int pch = ((kt * 4 + lg) ^ sw) * 8;
        short8 a0 = *(const short8*)(A + (wbase + lr) * 128 + pch);
        short8 a1 = *(const short8*)(A + (wbase + 16 + lr) * 128 + pch);
#pragma unroll
        for (int n = 0; n < 8; ++n) {
            short8 b = Wp[(n * 4 + kt) * 64 + l];
            acc[0][n] = __builtin_amdgcn_mfma_f32_16x16x32_bf16(a0, b, acc[0][n], 0, 0, 0);
            acc[1][n] = __builtin_amdgcn_mfma_f32_16x16x32_bf16(a1, b, acc[1][n], 0, 0, 0);
        }
    }
#pragma unroll
    for (int n = 0; n < 8; ++n) {
        const int col = n * 16 + lr;
        const float bb = bias[col];
        const int cch = col >> 3, cof = col & 7;
#pragma unroll
        for (int m = 0; m < 2; ++m) {
#pragma unroll
            for (int r = 0; r < 4; ++r) {
                int row = wbase + m * 16 + lg * 4 + r;
                float t = fmaxf(acc[m][n][r] + bb, 0.f);
                D[row * 128 + ((cch ^ (row & 7)) * 8) + cof] = f2b(t);
            }
        }
    }
}

// Segmented pool of the LDS tile into pooled[g*384 + coloff + col].
__device__ __forceinline__ void pool_tile(const ushort* __restrict__ T,
                                          const int* __restrict__ batchl,
                                          float* __restrict__ pooled,
                                          int coloff, int tid) {
    int col = tid & 127, half = tid >> 7;
    int cch = col >> 3, cof = col & 7;
    float pacc = 0.f;
    int curg = -1;
    for (int r = half * 64; r < half * 64 + 64; ++r) {
        int g = batchl[r];
        if (g != curg) {
            if (curg >= 0) atomicAdd(&pooled[curg * 384 + coloff + col], pacc);
            curg = g;
            pacc = 0.f;
        }
        if (g >= 0) pacc += uf((uint)T[r * 128 + ((cch ^ (r & 7)) * 8) + cof] << 16);
    }
    if (curg >= 0) atomicAdd(&pooled[curg * 384 + coloff + col], pacc);
}

// ---------------------------------------------------------------------------
// Fused layer 1: h1 = relu(relu((x + agg(x)) @ W1 + b1) @ W2 + b2) + pool
// (round-8 version, unchanged)
// ---------------------------------------------------------------------------
__global__ __launch_bounds__(256) void fl1_k(const float* __restrict__ x,
                                             const int* __restrict__ batch,
                                             const int* __restrict__ row_start,
                                             const ushort* __restrict__ nbr,
                                             const float* __restrict__ W1, // 8x128
                                             const float* __restrict__ b1,
                                             const short8* __restrict__ Wp2,
                                             const float* __restrict__ b2,
                                             ushort* __restrict__ out,
                                             float* __restrict__ pooled, int nNodes) {
    __shared__ float hin[128][8];
    __shared__ __align__(16) ushort T[128 * 128];
    __shared__ int batchl[128];
    int t = threadIdx.x;
    int n0 = blockIdx.x * 128;
    if (t < 128) batchl[t] = (n0 + t < nNodes) ? batch[n0 + t] : -1;
    {   // gather-sum staging: 2 threads per row, unroll x8
        int r = t >> 1;
        int half = t & 1;
        int n = n0 + r;
        float4 v = make_float4(0.f, 0.f, 0.f, 0.f);
        if (n < nNodes) {
            v = *(const float4*)(x + (size_t)n * 8 + half * 4);
            int rs = row_start[n], re = row_start[n + 1];
            int p = rs;
#define AX(u) { v.x += u.x; v.y += u.y; v.z += u.z; v.w += u.w; }
            for (; p + 8 <= re; p += 8) {
                int s0 = nbr[p],     s1 = nbr[p + 1], s2 = nbr[p + 2], s3 = nbr[p + 3];
                int s4 = nbr[p + 4], s5 = nbr[p + 5], s6 = nbr[p + 6], s7 = nbr[p + 7];
                float4 u0 = *(const float4*)(x + (size_t)s0 * 8 + half * 4);
                float4 u1 = *(const float4*)(x + (size_t)s1 * 8 + half * 4);
                float4 u2 = *(const float4*)(x + (size_t)s2 * 8 + half * 4);
                float4 u3 = *(const float4*)(x + (size_t)s3 * 8 + half * 4);
                float4 u4 = *(const float4*)(x + (size_t)s4 * 8 + half * 4);
                float4 u5 = *(const float4*)(x + (size_t)s5 * 8 + half * 4);
                float4 u6 = *(const float4*)(x + (size_t)s6 * 8 + half * 4);
                float4 u7 = *(const float4*)(x + (size_t)s7 * 8 + half * 4);
                AX(u0) AX(u1) AX(u2) AX(u3) AX(u4) AX(u5) AX(u6) AX(u7)
            }
            for (; p < re; ++p) {
                int s = nbr[p];
                float4 u = *(const float4*)(x + (size_t)s * 8 + half * 4);
                AX(u)
            }
#undef AX
        }
        *(float4*)(&hin[r][half * 4]) = v;
    }
    __syncthreads();
    // MLP1 (8->128), bf16 result into swizzled T
    int tx = t & 15, ty = t >> 4;
    float w[8][8];
#pragma unroll
    for (int k = 0; k < 8; ++k) {
        float4 w0 = *(const float4*)(W1 + k * HD + tx * 8);
        float4 w1 = *(const float4*)(W1 + k * HD + tx * 8 + 4);
        w[k][0] = w0.x; w[k][1] = w0.y; w[k][2] = w0.z; w[k][3] = w0.w;
        w[k][4] = w1.x; w[k][5] = w1.y; w[k][6] = w1.z; w[k][7] = w1.w;
    }
    float4 c0 = *(const float4*)(b1 + tx * 8);
    float4 c1 = *(const float4*)(b1 + tx * 8 + 4);
    float bb[8] = {c0.x, c0.y, c0.z, c0.w, c1.x, c1.y, c1.z, c1.w};
#pragma unroll
    for (int i = 0; i < 8; ++i) {
        int r = ty * 8 + i;
        float4 a0 = *(const float4*)(&hin[r][0]);
        float4 a1 = *(const float4*)(&hin[r][4]);
        float a[8] = {a0.x, a0.y, a0.z, a0.w, a1.x, a1.y, a1.z, a1.w};
        short8 ov;
#pragma unroll
        for (int jj = 0; jj < 8; ++jj) {
            float acc = bb[jj];
#pragma unroll
            for (int k = 0; k < 8; ++k) acc += a[k] * w[k][jj];
            ov[jj] = (short)f2b(fmaxf(acc, 0.f));
        }
        *(short8*)(T + r * 128 + ((tx ^ (r & 7)) * 8)) = ov;
    }
    __syncthreads();
    gemm128(T, Wp2, b2, T, t);
    __syncthreads();
#pragma unroll
    for (int i = 0; i < 8; ++i) {
        int idx = i * 256 + t;
        int row = idx >> 4, ch = idx & 15;
        int n = n0 + row;
        if (n < nNodes) {
            short8 v = *(const short8*)(T + row * 128 + ((ch ^ (row & 7)) * 8));
            *(short8*)(out + (size_t)n * HD + ch * 8) = v;
        }
    }
    pool_tile(T, batchl, pooled, 0, t);
}

// ---------------------------------------------------------------------------
// Fused layers 2/3: gather-agg staging + GEMM1 + GEMM2 + pool, one kernel.
// Stage, GEMM1, GEMM2 are all WAVE-PRIVATE (wave w owns rows [32w,32w+32)):
// no syncthreads until the final store/pool -> waves free-run, one wave's
// MFMA overlaps another's gather. Half-wave per row gather (aggb structure),
// x8 unroll, fp32 accumulate. STORE=0 skips the global h-store (layer 3).
// ---------------------------------------------------------------------------
template <int STORE>
__global__ __launch_bounds__(256) void fmm_k(const ushort* __restrict__ Ain,
                                             const int* __restrict__ batch,
                                             const int* __restrict__ row_start,
                                             const ushort* __restrict__ nbr,
                                             const short8* __restrict__ Wp1,
                                             const float* __restrict__ b1,
                                             const short8* __restrict__ Wp2,
                                             const float* __restrict__ b2,
                                             ushort* __restrict__ out,
                                             float* __restrict__ pooled,
                                             int coloff, int nNodes) {
    __shared__ __align__(16) ushort T[128 * 128];
    __shared__ int batchl[128];
    const int t = threadIdx.x;
    const int n0 = blockIdx.x * 128;
    if (t < 128) batchl[t] = (n0 + t < nNodes) ? batch[n0 + t] : -1;
    // ---- fused gather-agg staging: half-wave (32 lanes) per row, 16 rows each
    {
        const int hw = t >> 5;          // 0..7
        const int sub = t & 31;         // uint2 slot (8B) within 256B row
        const uint2* hp = (const uint2*)Ain;
        for (int rr = 0; rr < 16; ++rr) {
            const int row = hw * 16 + rr;
            const int n = n0 + row;
            float f0 = 0.f, f1 = 0.f, f2v = 0.f, f3 = 0.f;
            if (n < nNodes) {
                uint2 u = hp[(size_t)n * 32 + sub];
                f0 = uf(u.x << 16); f1 = uf(u.x & 0xffff0000u);
                f2v = uf(u.y << 16); f3 = uf(u.y & 0xffff0000u);
                int rs = row_start[n], re = row_start[n + 1];
                int p = rs;
#define ACC4(vv) { f0 += uf(vv.x << 16); f1 += uf(vv.x & 0xffff0000u); \
                   f2v += uf(vv.y << 16); f3 += uf(vv.y & 0xffff0000u); }
                for (; p + 8 <= re; p += 8) {
                    int s0 = nbr[p],     s1 = nbr[p + 1], s2 = nbr[p + 2], s3 = nbr[p + 3];
                    int s4 = nbr[p + 4], s5 = nbr[p + 5], s6 = nbr[p + 6], s7 = nbr[p + 7];
                    uint2 v0 = hp[(size_t)s0 * 32 + sub];
                    uint2 v1 = hp[(size_t)s1 * 32 + sub];
                    uint2 v2 = hp[(size_t)s2 * 32 + sub];
                    uint2 v3 = hp[(size_t)s3 * 32 + sub];
                    uint2 v4 = hp[(size_t)s4 * 32 + sub];
                    uint2 v5 = hp[(size_t)s5 * 32 + sub];
                    uint2 v6 = hp[(size_t)s6 * 32 + sub];
                    uint2 v7 = hp[(size_t)s7 * 32 + sub];
                    ACC4(v0) ACC4(v1) ACC4(v2) ACC4(v3)
                    ACC4(v4) ACC4(v5) ACC4(v6) ACC4(v7)
                }
                for (; p + 4 <= re; p += 4) {
                    int s0 = nbr[p], s1 = nbr[p + 1], s2 = nbr[p + 2], s3 = nbr[p + 3];
                    uint2 v0 = hp[(size_t)s0 * 32 + sub];
                    uint2 v1 = hp[(size_t)s1 * 32 + sub];
                    uint2 v2 = hp[(size_t)s2 * 32 + sub];
                    uint2 v3 = hp[(size_t)s3 * 32 + sub];
                    ACC4(v0) ACC4(v1) ACC4(v2) ACC4(v3)
                }
                for (; p < re; ++p) {
                    int s = nbr[p];
                    uint2 v = hp[(size_t)s * 32 + sub];
                    ACC4(v)
                }
#undef ACC4
            }
            uint2 o;
            o.x = (uint)f2b(f0) | ((uint)f2b(f1) << 16);
            o.y = (uint)f2b(f2v) | ((uint)f2b(f3) << 16);
            // swizzled LDS write: chunk = sub>>1, half-chunk = sub&1
            *(uint2*)(T + row * 128 + (((sub >> 1) ^ (row & 7)) << 3)
                      + ((sub & 1) << 2)) = o;
        }
    }
    // wave-private rows: no barrier needed between stage/gemm1/gemm2
    gemm128(T, Wp1, b1, T, t);
    gemm128(T, Wp2, b2, T, t);
    __syncthreads();   // store/pool read all rows
    if constexpr (STORE) {
#pragma unroll
        for (int i = 0; i < 8; ++i) {
            int idx = i * 256 + t;
            int row = idx >> 4, ch = idx & 15;
            int n = n0 + row;
            if (n < nNodes) {
                short8 v = *(const short8*)(T + row * 128 + ((ch ^ (row & 7)) * 8));
                *(short8*)(out + (size_t)n * HD + ch * 8) = v;
            }
        }
    }
    pool_tile(T, batchl, pooled, coloff, t);
}

// ---------------------------------------------------------------------------
// Classifier (all fp32)
// ---------------------------------------------------------------------------
__global__ __launch_bounds__(256) void cls_k(const float* __restrict__ pooled,
                                             const float* __restrict__ W1,  // 384x256
                                             const float* __restrict__ b1,
                                             const float* __restrict__ gamma,
                                             const float* __restrict__ beta,
                                             const float* __restrict__ mean,
                                             const float* __restrict__ var,
                                             const float* __restrict__ W2,  // 256x4
                                             const float* __restrict__ b2,
                                             float* __restrict__ out) {
    __shared__ float pg[384];
    __shared__ float z[256];
    int g = blockIdx.x, j = threadIdx.x;
    pg[j] = pooled[g * 384 + j];
    if (j < 128) pg[256 + j] = pooled[g * 384 + 256 + j];
    __syncthreads();
    float acc = b1[j];
    for (int k = 0; k < 384; ++k) acc += pg[k] * W1[k * 256 + j];
    acc = (acc - mean[j]) * rsqrtf(var[j] + 1e-5f) * gamma[j] + beta[j];
    z[j] = fmaxf(acc, 0.f);
    __syncthreads();
    if (j < 4) {
        float o = b2[j];
        for (int k = 0; k < 256; ++k) o += z[k] * W2[k * 4 + j];
        out[g * 4 + j] = o;
    }
}

// ---------------------------------------------------------------------------
extern "C" void kernel_launch(void* const* d_in, const int* in_sizes, int n_in,
                              void* d_out, int out_size, void* d_ws, size_t ws_size,
                              hipStream_t stream) {
    const int N = NNODES, E = NEDGES;
    const float* x     = (const float*)d_in[0];
    const int*   ei    = (const int*)d_in[1];
    const int*   batch = (const int*)d_in[2];
    const float* l1W1 = (const float*)d_in[3];
    const float* l1b1 = (const float*)d_in[4];
    const float* l1W2 = (const float*)d_in[5];
    const float* l1b2 = (const float*)d_in[6];
    const float* l2W1 = (const float*)d_in[7];
    const float* l2b1 = (const float*)d_in[8];
    const float* l2W2 = (const float*)d_in[9];
    const float* l2b2 = (const float*)d_in[10];
    const float* l3W1 = (const float*)d_in[11];
    const float* l3b1 = (const float*)d_in[12];
    const float* l3W2 = (const float*)d_in[13];
    const float* l3b2 = (const float*)d_in[14];
    const float* cW1  = (const float*)d_in[15];
    const float* cb1  = (const float*)d_in[16];
    const float* bnG  = (const float*)d_in[17];
    const float* bnB  = (const float*)d_in[18];
    const float* bnM  = (const float*)d_in[19];
    const float* bnV  = (const float*)d_in[20];
    const float* cW2  = (const float*)d_in[21];
    const float* cb2  = (const float*)d_in[22];

    const int* src = ei;
    const int* dst = ei + E;

    // ---- workspace layout ----
    char* wsp = (char*)d_ws;
    ushort* h1   = (ushort*)wsp;  wsp += (size_t)N * HD * 2;
    ushort* h2   = (ushort*)wsp;  wsp += (size_t)N * HD * 2;
    float* pooled = (float*)wsp;  wsp += (size_t)64 * 384 * 4;
    ushort* wp    = (ushort*)wsp; wsp += (size_t)5 * 16384 * 2;
    int* count    = (int*)wsp;    wsp += (size_t)N * 4;
    int* row_tmp  = (int*)wsp;    wsp += (size_t)N * 4;
    int* blocksum = (int*)wsp;    wsp += 256 * 4;
    int* row_start = (int*)wsp;   wsp += (size_t)(N + 1) * 4;
    int* cur       = (int*)wsp;   wsp += (size_t)N * 4;
    ushort* nbr    = (ushort*)wsp; wsp += (size_t)E * 2;

    const int nB = (N + 255) / 256;              // 196
    wpinit_k<<<dim3(8, 5), 256, 0, stream>>>(l1W2, l2W1, l2W2, l3W1, l3W2,
                                             wp, count, pooled);
    phist_k<<<2048, 256, 0, stream>>>(dst, count, E);
    scan1_k<<<nB, 256, 0, stream>>>(count, row_tmp, blocksum, N);
    scan23_k<<<nB, 256, 0, stream>>>(count, row_tmp, blocksum, nB, row_start, cur, N, E);
    pscatter_k<<<2048, 256, 0, stream>>>(src, dst, cur, nbr, E);

    const short8* Wp0 = (const short8*)(wp);
    const short8* Wp1 = (const short8*)(wp + 16384);
    const short8* Wp2 = (const short8*)(wp + 2 * 16384);
    const short8* Wp3 = (const short8*)(wp + 3 * 16384);
    const short8* Wp4 = (const short8*)(wp + 4 * 16384);

    const int mb = (N + 127) / 128;              // 391 tiles
    // layer 1 (gather + MLP1 + GEMM2 + pool fused)
    fl1_k<<<mb, 256, 0, stream>>>(x, batch, row_start, nbr, l1W1, l1b1, Wp0, l1b2,
                                  h1, pooled, N);
    // layer 2: fused gather-agg + MLP + pool (h1 -> h2)
    fmm_k<1><<<mb, 256, 0, stream>>>(h1, batch, row_start, nbr, Wp1, l2b1, Wp2, l2b2,
                                     h2, pooled, 128, N);
    // layer 3: fused, no h3 store
    fmm_k<0><<<mb, 256, 0, stream>>>(h2, batch, row_start, nbr, Wp3, l3b1, Wp4, l3b2,
                                     nullptr, pooled, 256, N);
    // classifier
    cls_k<<<NGRAPH, 256, 0, stream>>>(pooled, cW1, cb1, bnG, bnB, bnM, bnV, cW2, cb2,
                                      (float*)d_out);
}

// Round 12
// 221.938 us; speedup vs baseline: 2.2243x; 1.2181x over previous
//
#include <hip/hip_runtime.h>
#include <hip/hip_bf16.h>

#define NNODES 50000
#define NEDGES 640000
#define NGRAPH 64
#define HD     128
#define NPART  8
#define PRANGE (NNODES / NPART)   // 6250 (dst-range partition for CSR build)

typedef __attribute__((ext_vector_type(8))) short short8;
typedef __attribute__((ext_vector_type(4))) float f32x4;

__device__ __forceinline__ float uf(uint u) { return __uint_as_float(u); }
// fp32 -> bf16 round-to-nearest-even
__device__ __forceinline__ ushort f2b(float f) {
    uint u = __float_as_uint(f);
    return (ushort)((u + 0x7fffu + ((u >> 16) & 1u)) >> 16);
}

// ---------------------------------------------------------------------------
// wpinit: pack 5 fp32 128x128 weights into bf16 MFMA B-fragment order,
// AND zero count[] + pooled[].
// ---------------------------------------------------------------------------
__global__ __launch_bounds__(256) void wpinit_k(const float* __restrict__ W0,
                                                const float* __restrict__ W1,
                                                const float* __restrict__ W2,
                                                const float* __restrict__ W3,
                                                const float* __restrict__ W4,
                                                ushort* __restrict__ Wp,
                                                int* __restrict__ count,
                                                float* __restrict__ pooled) {
    int which = blockIdx.y;
    const float* W = (which == 0) ? W0 : (which == 1) ? W1 : (which == 2) ? W2
                   : (which == 3) ? W3 : W4;
    ushort* dst = Wp + (size_t)which * 16384;
    int idx = blockIdx.x * 256 + threadIdx.x;   // 0..2047
    int l  = idx & 63;
    int kt = (idx >> 6) & 3;
    int nt = idx >> 8;
    int krow = kt * 32 + (l >> 4) * 8;
    int col  = nt * 16 + (l & 15);
    short8 v;
#pragma unroll
    for (int j = 0; j < 8; ++j) v[j] = (short)f2b(W[(size_t)(krow + j) * HD + col]);
    *(short8*)(dst + ((size_t)(nt * 4 + kt) * 64 + l) * 8) = v;
    int fid = (blockIdx.y * 8 + blockIdx.x) * 256 + threadIdx.x;
    for (int i = fid; i < NNODES; i += 10240) count[i] = 0;
    for (int i = fid; i < NGRAPH * 384; i += 10240) pooled[i] = 0.f;
}

// ---------------------------------------------------------------------------
// CSR build (round-8 structure: separate kernels, XCD dst-range partitioned)
// ---------------------------------------------------------------------------
__global__ __launch_bounds__(256) void phist_k(const int* __restrict__ dst,
                                               int* __restrict__ count, int E) {
    int p = blockIdx.x & 7;
    int q = blockIdx.x >> 3;
    int lo = p * PRANGE, hi = lo + PRANGE;
    for (int e = q * 256 + threadIdx.x; e < E; e += 256 * 256) {
        int d = dst[e];
        if (d >= lo && d < hi) atomicAdd(&count[d], 1);
    }
}

__global__ __launch_bounds__(256) void scan1_k(const int* __restrict__ count,
                                               int* __restrict__ row_tmp,
                                               int* __restrict__ blocksum, int N) {
    __shared__ int s[256];
    int t = threadIdx.x;
    int i = blockIdx.x * 256 + t;
    int v = (i < N) ? count[i] : 0;
    s[t] = v;
    __syncthreads();
    for (int off = 1; off < 256; off <<= 1) {
        int nv = s[t];
        if (t >= off) nv += s[t - off];
        __syncthreads();
        s[t] = nv;
        __syncthreads();
    }
    if (i < N) row_tmp[i] = s[t];
    if (t == 255) blocksum[blockIdx.x] = s[255];
}

__global__ __launch_bounds__(256) void scan23_k(const int* __restrict__ count,
                                                const int* __restrict__ row_tmp,
                                                const int* __restrict__ blocksum,
                                                int nB,
                                                int* __restrict__ row_start,
                                                int* __restrict__ cur, int N, int E) {
    __shared__ int s[256];
    int t = threadIdx.x;
    s[t] = (t < nB) ? blocksum[t] : 0;
    __syncthreads();
    for (int off = 1; off < 256; off <<= 1) {
        int nv = s[t];
        if (t >= off) nv += s[t - off];
        __syncthreads();
        s[t] = nv;
        __syncthreads();
    }
    int bid = blockIdx.x;
    int boff = (bid == 0) ? 0 : s[bid - 1];
    int i = bid * 256 + t;
    if (i < N) {
        int excl = row_tmp[i] - count[i] + boff;
        row_start[i] = excl;
        cur[i] = excl;
    }
    if (i == N) row_start[N] = E;
}

__global__ __launch_bounds__(256) void pscatter_k(const int* __restrict__ src,
                                                  const int* __restrict__ dst,
                                                  int* __restrict__ cur,
                                                  ushort* __restrict__ nbr, int E) {
    int p = blockIdx.x & 7;
    int q = blockIdx.x >> 3;
    int lo = p * PRANGE, hi = lo + PRANGE;
    for (int e = q * 256 + threadIdx.x; e < E; e += 256 * 256) {
        int d = dst[e];
        if (d >= lo && d < hi) {
            int pos = atomicAdd(&cur[d], 1);
            nbr[pos] = (ushort)src[e];
        }
    }
}

// ---------------------------------------------------------------------------
// bf16 aggregation (round-8 version): out[n] = h[n] + sum h[s].
// 2 nodes per wave; neighbor walk unrolled x8. 6250 blocks -> high occupancy.
// ---------------------------------------------------------------------------
__global__ __launch_bounds__(256) void aggb_k(const ushort* __restrict__ h,
                                              const int* __restrict__ row_start,
                                              const ushort* __restrict__ nbr,
                                              ushort* __restrict__ out, int nNodes) {
    int gw   = (blockIdx.x * 256 + threadIdx.x) >> 6;
    int lane = threadIdx.x & 63;
    int node = gw * 2 + (lane >> 5);
    int sub  = lane & 31;
    if (node >= nNodes) return;
    const uint2* hp = (const uint2*)h;
    uint2 u = hp[(size_t)node * 32 + sub];
    float f0 = uf(u.x << 16), f1 = uf(u.x & 0xffff0000u);
    float f2v = uf(u.y << 16), f3 = uf(u.y & 0xffff0000u);
    int rs = row_start[node], re = row_start[node + 1];
    int p = rs;
#define ACC4(vv) { f0 += uf(vv.x << 16); f1 += uf(vv.x & 0xffff0000u); \
                   f2v += uf(vv.y << 16); f3 += uf(vv.y & 0xffff0000u); }
    for (; p + 8 <= re; p += 8) {
        int s0 = nbr[p],     s1 = nbr[p + 1], s2 = nbr[p + 2], s3 = nbr[p + 3];
        int s4 = nbr[p + 4], s5 = nbr[p + 5], s6 = nbr[p + 6], s7 = nbr[p + 7];
        uint2 v0 = hp[(size_t)s0 * 32 + sub];
        uint2 v1 = hp[(size_t)s1 * 32 + sub];
        uint2 v2 = hp[(size_t)s2 * 32 + sub];
        uint2 v3 = hp[(size_t)s3 * 32 + sub];
        uint2 v4 = hp[(size_t)s4 * 32 + sub];
        uint2 v5 = hp[(size_t)s5 * 32 + sub];
        uint2 v6 = hp[(size_t)s6 * 32 + sub];
        uint2 v7 = hp[(size_t)s7 * 32 + sub];
        ACC4(v0) ACC4(v1) ACC4(v2) ACC4(v3)
        ACC4(v4) ACC4(v5) ACC4(v6) ACC4(v7)
    }
    for (; p + 4 <= re; p += 4) {
        int s0 = nbr[p], s1 = nbr[p + 1], s2 = nbr[p + 2], s3 = nbr[p + 3];
        uint2 v0 = hp[(size_t)s0 * 32 + sub];
        uint2 v1 = hp[(size_t)s1 * 32 + sub];
        uint2 v2 = hp[(size_t)s2 * 32 + sub];
        uint2 v3 = hp[(size_t)s3 * 32 + sub];
        ACC4(v0) ACC4(v1) ACC4(v2) ACC4(v3)
    }
    for (; p < re; ++p) {
        int s = nbr[p];
        uint2 v = hp[(size_t)s * 32 + sub];
        ACC4(v)
    }
#undef ACC4
    uint2 o;
    o.x = (uint)f2b(f0) | ((uint)f2b(f1) << 16);
    o.y = (uint)f2b(f2v) | ((uint)f2b(f3) << 16);
    ((uint2*)out)[(size_t)node * 32 + sub] = o;
}

// ---------------------------------------------------------------------------
// 64x128 bf16 MFMA GEMM step on an LDS tile. Wave-private rows:
// wave w reads/writes only rows [16w, 16w+16). D = bf16(relu(A @ Wp + bias)).
// M=64 tile -> 782 blocks, ~2x occupancy vs M=128 (staging latency hiding).
// ---------------------------------------------------------------------------
__device__ __forceinline__ void gemm64(const ushort* __restrict__ A,
                                       const short8* __restrict__ Wp,
                                       const float* __restrict__ bias,
                                       ushort* __restrict__ D, int tid) {
    const int l = tid & 63, w = tid >> 6;
    const int lr = l & 15, lg = l >> 4;
    const int wbase = w * 16;
    const int sw = lr & 7;
    f32x4 acc[8];
    const f32x4 z4 = {0.f, 0.f, 0.f, 0.f};
#pragma unroll
    for (int n = 0; n < 8; ++n) acc[n] = z4;
#pragma unroll
    for (int kt = 0; kt < 4; ++kt) {
        const int pch = ((kt * 4 + lg) ^ sw) * 8;
        short8 a0 = *(const short8*)(A + (wbase + lr) * 128 + pch);
#pragma unroll
        for (int n = 0; n < 8; ++n) {
            short8 b = Wp[(n * 4 + kt) * 64 + l];
            acc[n] = __builtin_amdgcn_mfma_f32_16x16x32_bf16(a0, b, acc[n], 0, 0, 0);
        }
    }
#pragma unroll
    for (int n = 0; n < 8; ++n) {
        const int col = n * 16 + lr;
        const float bb = bias[col];
        const int cch = col >> 3, cof = col & 7;
#pragma unroll
        for (int r = 0; r < 4; ++r) {
            int row = wbase + lg * 4 + r;
            float t = fmaxf(acc[n][r] + bb, 0.f);
            D[row * 128 + ((cch ^ (row & 7)) * 8) + cof] = f2b(t);
        }
    }
}

// Segmented pool of a 64-row LDS tile into pooled[g*384 + coloff + col].
__device__ __forceinline__ void pool_tile64(const ushort* __restrict__ T,
                                            const int* __restrict__ batchl,
                                            float* __restrict__ pooled,
                                            int coloff, int tid) {
    int col = tid & 127, half = tid >> 7;
    int cch = col >> 3, cof = col & 7;
    float pacc = 0.f;
    int curg = -1;
    for (int r = half * 32; r < half * 32 + 32; ++r) {
        int g = batchl[r];
        if (g != curg) {
            if (curg >= 0) atomicAdd(&pooled[curg * 384 + coloff + col], pacc);
            curg = g;
            pacc = 0.f;
        }
        if (g >= 0) pacc += uf((uint)T[r * 128 + ((cch ^ (r & 7)) * 8) + cof] << 16);
    }
    if (curg >= 0) atomicAdd(&pooled[curg * 384 + coloff + col], pacc);
}

// ---------------------------------------------------------------------------
// Fused layer 1 (M=64): h1 = relu(relu((x + agg(x)) @ W1 + b1) @ W2 + b2) + pool
// Gather: 4 threads per row (float2 slots), unroll x8.
// ---------------------------------------------------------------------------
__global__ __launch_bounds__(256) void fl1_k(const float* __restrict__ x,
                                             const int* __restrict__ batch,
                                             const int* __restrict__ row_start,
                                             const ushort* __restrict__ nbr,
                                             const float* __restrict__ W1, // 8x128
                                             const float* __restrict__ b1,
                                             const short8* __restrict__ Wp2,
                                             const float* __restrict__ b2,
                                             ushort* __restrict__ out,
                                             float* __restrict__ pooled, int nNodes) {
    __shared__ float hin[64][8];
    __shared__ __align__(16) ushort T[64 * 128];
    __shared__ int batchl[64];
    int t = threadIdx.x;
    int n0 = blockIdx.x * 64;
    if (t < 64) batchl[t] = (n0 + t < nNodes) ? batch[n0 + t] : -1;
    {   // gather-sum staging: 4 threads per row (float2 each), unroll x8
        int r = t >> 2;
        int slot = t & 3;
        int n = n0 + r;
        float2 v = make_float2(0.f, 0.f);
        if (n < nNodes) {
            v = *(const float2*)(x + (size_t)n * 8 + slot * 2);
            int rs = row_start[n], re = row_start[n + 1];
            int p = rs;
#define AX(u) { v.x += u.x; v.y += u.y; }
            for (; p + 8 <= re; p += 8) {
                int s0 = nbr[p],     s1 = nbr[p + 1], s2 = nbr[p + 2], s3 = nbr[p + 3];
                int s4 = nbr[p + 4], s5 = nbr[p + 5], s6 = nbr[p + 6], s7 = nbr[p + 7];
                float2 u0 = *(const float2*)(x + (size_t)s0 * 8 + slot * 2);
                float2 u1 = *(const float2*)(x + (size_t)s1 * 8 + slot * 2);
                float2 u2 = *(const float2*)(x + (size_t)s2 * 8 + slot * 2);
                float2 u3 = *(const float2*)(x + (size_t)s3 * 8 + slot * 2);
                float2 u4 = *(const float2*)(x + (size_t)s4 * 8 + slot * 2);
                float2 u5 = *(const float2*)(x + (size_t)s5 * 8 + slot * 2);
                float2 u6 = *(const float2*)(x + (size_t)s6 * 8 + slot * 2);
                float2 u7 = *(const float2*)(x + (size_t)s7 * 8 + slot * 2);
                AX(u0) AX(u1) AX(u2) AX(u3) AX(u4) AX(u5) AX(u6) AX(u7)
            }
            for (; p < re; ++p) {
                int s = nbr[p];
                float2 u = *(const float2*)(x + (size_t)s * 8 + slot * 2);
                AX(u)
            }
#undef AX
        }
        hin[r][slot * 2]     = v.x;
        hin[r][slot * 2 + 1] = v.y;
    }
    __syncthreads();
    // MLP1 (8->128): thread = (ty: 4 rows, tx: 8 cols), bf16 into swizzled T
    int tx = t & 15, ty = t >> 4;          // ty in [0,16): rows ty*4..ty*4+4
    float w[8][8];
#pragma unroll
    for (int k = 0; k < 8; ++k) {
        float4 w0 = *(const float4*)(W1 + k * HD + tx * 8);
        float4 w1 = *(const float4*)(W1 + k * HD + tx * 8 + 4);
        w[k][0] = w0.x; w[k][1] = w0.y; w[k][2] = w0.z; w[k][3] = w0.w;
        w[k][4] = w1.x; w[k][5] = w1.y; w[k][6] = w1.z; w[k][7] = w1.w;
    }
    float4 c0 = *(const float4*)(b1 + tx * 8);
    float4 c1 = *(const float4*)(b1 + tx * 8 + 4);
    float bb[8] = {c0.x, c0.y, c0.z, c0.w, c1.x, c1.y, c1.z, c1.w};
#pragma unroll
    for (int i = 0; i < 4; ++i) {
        int r = ty * 4 + i;
        float4 a0 = *(const float4*)(&hin[r][0]);
        float4 a1 = *(const float4*)(&hin[r][4]);
        float a[8] = {a0.x, a0.y, a0.z, a0.w, a1.x, a1.y, a1.z, a1.w};
        short8 ov;
#pragma unroll
        for (int jj = 0; jj < 8; ++jj) {
            float acc = bb[jj];
#pragma unroll
            for (int k = 0; k < 8; ++k) acc += a[k] * w[k][jj];
            ov[jj] = (short)f2b(fmaxf(acc, 0.f));
        }
        *(short8*)(T + r * 128 + ((tx ^ (r & 7)) * 8)) = ov;
    }
    __syncthreads();
    gemm64(T, Wp2, b2, T, t);      // in-place, wave-private rows
    __syncthreads();
#pragma unroll
    for (int i = 0; i < 4; ++i) {
        int idx = i * 256 + t;
        int row = idx >> 4, ch = idx & 15;
        int n = n0 + row;
        if (n < nNodes) {
            short8 v = *(const short8*)(T + row * 128 + ((ch ^ (row & 7)) * 8));
            *(short8*)(out + (size_t)n * HD + ch * 8) = v;
        }
    }
    pool_tile64(T, batchl, pooled, 0, t);
}

// ---------------------------------------------------------------------------
// Fused layer MLP (layers 2,3; M=64): out = relu(relu(A@W1+b1)@W2+b2) + pool.
// STORE=0 skips the global h-store (layer 3).
// ---------------------------------------------------------------------------
template <int STORE>
__global__ __launch_bounds__(256) void fmm_k(const ushort* __restrict__ Ain,
                                             const int* __restrict__ batch,
                                             const short8* __restrict__ Wp1,
                                             const float* __restrict__ b1,
                                             const short8* __restrict__ Wp2,
                                             const float* __restrict__ b2,
                                             ushort* __restrict__ out,
                                             float* __restrict__ pooled,
                                             int coloff, int nNodes) {
    __shared__ __align__(16) ushort T[64 * 128];
    __shared__ int batchl[64];
    const int t = threadIdx.x;
    const int n0 = blockIdx.x * 64;
    if (t < 64) batchl[t] = (n0 + t < nNodes) ? batch[n0 + t] : -1;
#pragma unroll
    for (int i = 0; i < 4; ++i) {
        int idx = i * 256 + t;
        int row = idx >> 4, ch = idx & 15;
        short8 v = {0, 0, 0, 0, 0, 0, 0, 0};
        int n = n0 + row;
        if (n < nNodes) v = *(const short8*)(Ain + (size_t)n * HD + ch * 8);
        *(short8*)(T + row * 128 + ((ch ^ (row & 7)) * 8)) = v;
    }
    __syncthreads();
    gemm64(T, Wp1, b1, T, t);      // wave-private rows: no barrier needed between
    gemm64(T, Wp2, b2, T, t);      // gemm1 and gemm2
    __syncthreads();
    if constexpr (STORE) {
#pragma unroll
        for (int i = 0; i < 4; ++i) {
            int idx = i * 256 + t;
            int row = idx >> 4, ch = idx & 15;
            int n = n0 + row;
            if (n < nNodes) {
                short8 v = *(const short8*)(T + row * 128 + ((ch ^ (row & 7)) * 8));
                *(short8*)(out + (size_t)n * HD + ch * 8) = v;
            }
        }
    }
    pool_tile64(T, batchl, pooled, coloff, t);
}

// ---------------------------------------------------------------------------
// Classifier (all fp32)
// ---------------------------------------------------------------------------
__global__ __launch_bounds__(256) void cls_k(const float* __restrict__ pooled,
                                             const float* __restrict__ W1,  // 384x256
                                             const float* __restrict__ b1,
                                             const float* __restrict__ gamma,
                                             const float* __restrict__ beta,
                                             const float* __restrict__ mean,
                                             const float* __restrict__ var,
                                             const float* __restrict__ W2,  // 256x4
                                             const float* __restrict__ b2,
                                             float* __restrict__ out) {
    __shared__ float pg[384];
    __shared__ float z[256];
    int g = blockIdx.x, j = threadIdx.x;
    pg[j] = pooled[g * 384 + j];
    if (j < 128) pg[256 + j] = pooled[g * 384 + 256 + j];
    __syncthreads();
    float acc = b1[j];
    for (int k = 0; k < 384; ++k) acc += pg[k] * W1[k * 256 + j];
    acc = (acc - mean[j]) * rsqrtf(var[j] + 1e-5f) * gamma[j] + beta[j];
    z[j] = fmaxf(acc, 0.f);
    __syncthreads();
    if (j < 4) {
        float o = b2[j];
        for (int k = 0; k < 256; ++k) o += z[k] * W2[k * 4 + j];
        out[g * 4 + j] = o;
    }
}

// ---------------------------------------------------------------------------
extern "C" void kernel_launch(void* const* d_in, const int* in_sizes, int n_in,
                              void* d_out, int out_size, void* d_ws, size_t ws_size,
                              hipStream_t stream) {
    const int N = NNODES, E = NEDGES;
    const float* x     = (const float*)d_in[0];
    const int*   ei    = (const int*)d_in[1];
    const int*   batch = (const int*)d_in[2];
    const float* l1W1 = (const float*)d_in[3];
    const float* l1b1 = (const float*)d_in[4];
    const float* l1W2 = (const float*)d_in[5];
    const float* l1b2 = (const float*)d_in[6];
    const float* l2W1 = (const float*)d_in[7];
    const float* l2b1 = (const float*)d_in[8];
    const float* l2W2 = (const float*)d_in[9];
    const float* l2b2 = (const float*)d_in[10];
    const float* l3W1 = (const float*)d_in[11];
    const float* l3b1 = (const float*)d_in[12];
    const float* l3W2 = (const float*)d_in[13];
    const float* l3b2 = (const float*)d_in[14];
    const float* cW1  = (const float*)d_in[15];
    const float* cb1  = (const float*)d_in[16];
    const float* bnG  = (const float*)d_in[17];
    const float* bnB  = (const float*)d_in[18];
    const float* bnM  = (const float*)d_in[19];
    const float* bnV  = (const float*)d_in[20];
    const float* cW2  = (const float*)d_in[21];
    const float* cb2  = (const float*)d_in[22];

    const int* src = ei;
    const int* dst = ei + E;

    // ---- workspace layout ----
    char* wsp = (char*)d_ws;
    ushort* tmpb = (ushort*)wsp;  wsp += (size_t)N * HD * 2;
    ushort* h1   = (ushort*)wsp;  wsp += (size_t)N * HD * 2;
    ushort* h2   = (ushort*)wsp;  wsp += (size_t)N * HD * 2;
    float* pooled = (float*)wsp;  wsp += (size_t)64 * 384 * 4;
    ushort* wp    = (ushort*)wsp; wsp += (size_t)5 * 16384 * 2;
    int* count    = (int*)wsp;    wsp += (size_t)N * 4;
    int* row_tmp  = (int*)wsp;    wsp += (size_t)N * 4;
    int* blocksum = (int*)wsp;    wsp += 256 * 4;
    int* row_start = (int*)wsp;   wsp += (size_t)(N + 1) * 4;
    int* cur       = (int*)wsp;   wsp += (size_t)N * 4;
    ushort* nbr    = (ushort*)wsp; wsp += (size_t)E * 2;

    const int nB = (N + 255) / 256;              // 196
    wpinit_k<<<dim3(8, 5), 256, 0, stream>>>(l1W2, l2W1, l2W2, l3W1, l3W2,
                                             wp, count, pooled);
    phist_k<<<2048, 256, 0, stream>>>(dst, count, E);
    scan1_k<<<nB, 256, 0, stream>>>(count, row_tmp, blocksum, N);
    scan23_k<<<nB, 256, 0, stream>>>(count, row_tmp, blocksum, nB, row_start, cur, N, E);
    pscatter_k<<<2048, 256, 0, stream>>>(src, dst, cur, nbr, E);

    const short8* Wp0 = (const short8*)(wp);
    const short8* Wp1 = (const short8*)(wp + 16384);
    const short8* Wp2 = (const short8*)(wp + 2 * 16384);
    const short8* Wp3 = (const short8*)(wp + 3 * 16384);
    const short8* Wp4 = (const short8*)(wp + 4 * 16384);

    const int mb64 = (N + 63) / 64;              // 782 tiles
    const int ab = ((N + 1) / 2 * 64) / 256;     // 6250 blocks
    // layer 1 (gather + MLP1 + GEMM2 + pool fused)
    fl1_k<<<mb64, 256, 0, stream>>>(x, batch, row_start, nbr, l1W1, l1b1, Wp0, l1b2,
                                    h1, pooled, N);
    // layer 2
    aggb_k<<<ab, 256, 0, stream>>>(h1, row_start, nbr, tmpb, N);
    fmm_k<1><<<mb64, 256, 0, stream>>>(tmpb, batch, Wp1, l2b1, Wp2, l2b2, h2,
                                       pooled, 128, N);
    // layer 3 (no h3 store)
    aggb_k<<<ab, 256, 0, stream>>>(h2, row_start, nbr, tmpb, N);
    fmm_k<0><<<mb64, 256, 0, stream>>>(tmpb, batch, Wp3, l3b1, Wp4, l3b2, nullptr,
                                       pooled, 256, N);
    // classifier
    cls_k<<<NGRAPH, 256, 0, stream>>>(pooled, cW1, cb1, bnG, bnB, bnM, bnV, cW2, cb2,
                                      (float*)d_out);
}

// Round 13
// 221.017 us; speedup vs baseline: 2.2336x; 1.0042x over previous
//
#include <hip/hip_runtime.h>
#include <hip/hip_bf16.h>

#define NNODES 50000
#define NEDGES 640000
#define NGRAPH 64
#define HD     128
#define NPART  8
#define PRANGE (NNODES / NPART)   // 6250 (dst-range partition for CSR build)

typedef __attribute__((ext_vector_type(8))) short short8;
typedef __attribute__((ext_vector_type(4))) float f32x4;

__device__ __forceinline__ float uf(uint u) { return __uint_as_float(u); }
// fp32 -> bf16 round-to-nearest-even
__device__ __forceinline__ ushort f2b(float f) {
    uint u = __float_as_uint(f);
    return (ushort)((u + 0x7fffu + ((u >> 16) & 1u)) >> 16);
}

// ---------------------------------------------------------------------------
// wpinit: pack 5 fp32 128x128 weights into bf16 MFMA B-fragment order,
// AND zero count[] + pooled[].
// ---------------------------------------------------------------------------
__global__ __launch_bounds__(256) void wpinit_k(const float* __restrict__ W0,
                                                const float* __restrict__ W1,
                                                const float* __restrict__ W2,
                                                const float* __restrict__ W3,
                                                const float* __restrict__ W4,
                                                ushort* __restrict__ Wp,
                                                int* __restrict__ count,
                                                float* __restrict__ pooled) {
    int which = blockIdx.y;
    const float* W = (which == 0) ? W0 : (which == 1) ? W1 : (which == 2) ? W2
                   : (which == 3) ? W3 : W4;
    ushort* dst = Wp + (size_t)which * 16384;
    int idx = blockIdx.x * 256 + threadIdx.x;   // 0..2047
    int l  = idx & 63;
    int kt = (idx >> 6) & 3;
    int nt = idx >> 8;
    int krow = kt * 32 + (l >> 4) * 8;
    int col  = nt * 16 + (l & 15);
    short8 v;
#pragma unroll
    for (int j = 0; j < 8; ++j) v[j] = (short)f2b(W[(size_t)(krow + j) * HD + col]);
    *(short8*)(dst + ((size_t)(nt * 4 + kt) * 64 + l) * 8) = v;
    int fid = (blockIdx.y * 8 + blockIdx.x) * 256 + threadIdx.x;
    for (int i = fid; i < NNODES; i += 10240) count[i] = 0;
    for (int i = fid; i < NGRAPH * 384; i += 10240) pooled[i] = 0.f;
}

// ---------------------------------------------------------------------------
// CSR build (round-8 structure: separate kernels, XCD dst-range partitioned)
// ---------------------------------------------------------------------------
__global__ __launch_bounds__(256) void phist_k(const int* __restrict__ dst,
                                               int* __restrict__ count, int E) {
    int p = blockIdx.x & 7;
    int q = blockIdx.x >> 3;
    int lo = p * PRANGE, hi = lo + PRANGE;
    for (int e = q * 256 + threadIdx.x; e < E; e += 256 * 256) {
        int d = dst[e];
        if (d >= lo && d < hi) atomicAdd(&count[d], 1);
    }
}

__global__ __launch_bounds__(256) void scan1_k(const int* __restrict__ count,
                                               int* __restrict__ row_tmp,
                                               int* __restrict__ blocksum, int N) {
    __shared__ int s[256];
    int t = threadIdx.x;
    int i = blockIdx.x * 256 + t;
    int v = (i < N) ? count[i] : 0;
    s[t] = v;
    __syncthreads();
    for (int off = 1; off < 256; off <<= 1) {
        int nv = s[t];
        if (t >= off) nv += s[t - off];
        __syncthreads();
        s[t] = nv;
        __syncthreads();
    }
    if (i < N) row_tmp[i] = s[t];
    if (t == 255) blocksum[blockIdx.x] = s[255];
}

__global__ __launch_bounds__(256) void scan23_k(const int* __restrict__ count,
                                                const int* __restrict__ row_tmp,
                                                const int* __restrict__ blocksum,
                                                int nB,
                                                int* __restrict__ row_start,
                                                int* __restrict__ cur, int N, int E) {
    __shared__ int s[256];
    int t = threadIdx.x;
    s[t] = (t < nB) ? blocksum[t] : 0;
    __syncthreads();
    for (int off = 1; off < 256; off <<= 1) {
        int nv = s[t];
        if (t >= off) nv += s[t - off];
        __syncthreads();
        s[t] = nv;
        __syncthreads();
    }
    int bid = blockIdx.x;
    int boff = (bid == 0) ? 0 : s[bid - 1];
    int i = bid * 256 + t;
    if (i < N) {
        int excl = row_tmp[i] - count[i] + boff;
        row_start[i] = excl;
        cur[i] = excl;
    }
    if (i == N) row_start[N] = E;
}

__global__ __launch_bounds__(256) void pscatter_k(const int* __restrict__ src,
                                                  const int* __restrict__ dst,
                                                  int* __restrict__ cur,
                                                  ushort* __restrict__ nbr, int E) {
    int p = blockIdx.x & 7;
    int q = blockIdx.x >> 3;
    int lo = p * PRANGE, hi = lo + PRANGE;
    for (int e = q * 256 + threadIdx.x; e < E; e += 256 * 256) {
        int d = dst[e];
        if (d >= lo && d < hi) {
            int pos = atomicAdd(&cur[d], 1);
            nbr[pos] = (ushort)src[e];
        }
    }
}

// ---------------------------------------------------------------------------
// bf16 aggregation (round-8 version): out[n] = h[n] + sum h[s].
// 2 nodes per wave; neighbor walk unrolled x8. 6250 blocks -> high occupancy.
// ---------------------------------------------------------------------------
__global__ __launch_bounds__(256) void aggb_k(const ushort* __restrict__ h,
                                              const int* __restrict__ row_start,
                                              const ushort* __restrict__ nbr,
                                              ushort* __restrict__ out, int nNodes) {
    int gw   = (blockIdx.x * 256 + threadIdx.x) >> 6;
    int lane = threadIdx.x & 63;
    int node = gw * 2 + (lane >> 5);
    int sub  = lane & 31;
    if (node >= nNodes) return;
    const uint2* hp = (const uint2*)h;
    uint2 u = hp[(size_t)node * 32 + sub];
    float f0 = uf(u.x << 16), f1 = uf(u.x & 0xffff0000u);
    float f2v = uf(u.y << 16), f3 = uf(u.y & 0xffff0000u);
    int rs = row_start[node], re = row_start[node + 1];
    int p = rs;
#define ACC4(vv) { f0 += uf(vv.x << 16); f1 += uf(vv.x & 0xffff0000u); \
                   f2v += uf(vv.y << 16); f3 += uf(vv.y & 0xffff0000u); }
    for (; p + 8 <= re; p += 8) {
        int s0 = nbr[p],     s1 = nbr[p + 1], s2 = nbr[p + 2], s3 = nbr[p + 3];
        int s4 = nbr[p + 4], s5 = nbr[p + 5], s6 = nbr[p + 6], s7 = nbr[p + 7];
        uint2 v0 = hp[(size_t)s0 * 32 + sub];
        uint2 v1 = hp[(size_t)s1 * 32 + sub];
        uint2 v2 = hp[(size_t)s2 * 32 + sub];
        uint2 v3 = hp[(size_t)s3 * 32 + sub];
        uint2 v4 = hp[(size_t)s4 * 32 + sub];
        uint2 v5 = hp[(size_t)s5 * 32 + sub];
        uint2 v6 = hp[(size_t)s6 * 32 + sub];
        uint2 v7 = hp[(size_t)s7 * 32 + sub];
        ACC4(v0) ACC4(v1) ACC4(v2) ACC4(v3)
        ACC4(v4) ACC4(v5) ACC4(v6) ACC4(v7)
    }
    for (; p + 4 <= re; p += 4) {
        int s0 = nbr[p], s1 = nbr[p + 1], s2 = nbr[p + 2], s3 = nbr[p + 3];
        uint2 v0 = hp[(size_t)s0 * 32 + sub];
        uint2 v1 = hp[(size_t)s1 * 32 + sub];
        uint2 v2 = hp[(size_t)s2 * 32 + sub];
        uint2 v3 = hp[(size_t)s3 * 32 + sub];
        ACC4(v0) ACC4(v1) ACC4(v2) ACC4(v3)
    }
    for (; p < re; ++p) {
        int s = nbr[p];
        uint2 v = hp[(size_t)s * 32 + sub];
        ACC4(v)
    }
#undef ACC4
    uint2 o;
    o.x = (uint)f2b(f0) | ((uint)f2b(f1) << 16);
    o.y = (uint)f2b(f2v) | ((uint)f2b(f3) << 16);
    ((uint2*)out)[(size_t)node * 32 + sub] = o;
}

// ---------------------------------------------------------------------------
// 64x128 bf16 MFMA GEMM step on an LDS tile. Wave-private rows:
// wave w reads/writes only rows [16w, 16w+16). D = bf16(relu(A @ Wp + bias)).
// M=64 tile -> 782 blocks, ~2x occupancy vs M=128 (staging latency hiding).
// ---------------------------------------------------------------------------
__device__ __forceinline__ void gemm64(const ushort* __restrict__ A,
                                       const short8* __restrict__ Wp,
                                       const float* __restrict__ bias,
                                       ushort* __restrict__ D, int tid) {
    const int l = tid & 63, w = tid >> 6;
    const int lr = l & 15, lg = l >> 4;
    const int wbase = w * 16;
    const int sw = lr & 7;
    f32x4 acc[8];
    const f32x4 z4 = {0.f, 0.f, 0.f, 0.f};
#pragma unroll
    for (int n = 0; n < 8; ++n) acc[n] = z4;
#pragma unroll
    for (int kt = 0; kt < 4; ++kt) {
        const int pch = ((kt * 4 + lg) ^ sw) * 8;
        short8 a0 = *(const short8*)(A + (wbase + lr) * 128 + pch);
#pragma unroll
        for (int n = 0; n < 8; ++n) {
            short8 b = Wp[(n * 4 + kt) * 64 + l];
            acc[n] = __builtin_amdgcn_mfma_f32_16x16x32_bf16(a0, b, acc[n], 0, 0, 0);
        }
    }
#pragma unroll
    for (int n = 0; n < 8; ++n) {
        const int col = n * 16 + lr;
        const float bb = bias[col];
        const int cch = col >> 3, cof = col & 7;
#pragma unroll
        for (int r = 0; r < 4; ++r) {
            int row = wbase + lg * 4 + r;
            float t = fmaxf(acc[n][r] + bb, 0.f);
            D[row * 128 + ((cch ^ (row & 7)) * 8) + cof] = f2b(t);
        }
    }
}

// Segmented pool of a 64-row LDS tile into pooled[g*384 + coloff + col].
__device__ __forceinline__ void pool_tile64(const ushort* __restrict__ T,
                                            const int* __restrict__ batchl,
                                            float* __restrict__ pooled,
                                            int coloff, int tid) {
    int col = tid & 127, half = tid >> 7;
    int cch = col >> 3, cof = col & 7;
    float pacc = 0.f;
    int curg = -1;
    for (int r = half * 32; r < half * 32 + 32; ++r) {
        int g = batchl[r];
        if (g != curg) {
            if (curg >= 0) atomicAdd(&pooled[curg * 384 + coloff + col], pacc);
            curg = g;
            pacc = 0.f;
        }
        if (g >= 0) pacc += uf((uint)T[r * 128 + ((cch ^ (r & 7)) * 8) + cof] << 16);
    }
    if (curg >= 0) atomicAdd(&pooled[curg * 384 + coloff + col], pacc);
}

// ---------------------------------------------------------------------------
// Fused layer 1 (M=64): h1 = relu(relu((x + agg(x)) @ W1 + b1) @ W2 + b2) + pool
// Gather: 4 threads per row (float2 slots), unroll x8.
// ---------------------------------------------------------------------------
__global__ __launch_bounds__(256) void fl1_k(const float* __restrict__ x,
                                             const int* __restrict__ batch,
                                             const int* __restrict__ row_start,
                                             const ushort* __restrict__ nbr,
                                             const float* __restrict__ W1, // 8x128
                                             const float* __restrict__ b1,
                                             const short8* __restrict__ Wp2,
                                             const float* __restrict__ b2,
                                             ushort* __restrict__ out,
                                             float* __restrict__ pooled, int nNodes) {
    __shared__ float hin[64][8];
    __shared__ __align__(16) ushort T[64 * 128];
    __shared__ int batchl[64];
    int t = threadIdx.x;
    int n0 = blockIdx.x * 64;
    if (t < 64) batchl[t] = (n0 + t < nNodes) ? batch[n0 + t] : -1;
    {   // gather-sum staging: 4 threads per row (float2 each), unroll x8
        int r = t >> 2;
        int slot = t & 3;
        int n = n0 + r;
        float2 v = make_float2(0.f, 0.f);
        if (n < nNodes) {
            v = *(const float2*)(x + (size_t)n * 8 + slot * 2);
            int rs = row_start[n], re = row_start[n + 1];
            int p = rs;
#define AX(u) { v.x += u.x; v.y += u.y; }
            for (; p + 8 <= re; p += 8) {
                int s0 = nbr[p],     s1 = nbr[p + 1], s2 = nbr[p + 2], s3 = nbr[p + 3];
                int s4 = nbr[p + 4], s5 = nbr[p + 5], s6 = nbr[p + 6], s7 = nbr[p + 7];
                float2 u0 = *(const float2*)(x + (size_t)s0 * 8 + slot * 2);
                float2 u1 = *(const float2*)(x + (size_t)s1 * 8 + slot * 2);
                float2 u2 = *(const float2*)(x + (size_t)s2 * 8 + slot * 2);
                float2 u3 = *(const float2*)(x + (size_t)s3 * 8 + slot * 2);
                float2 u4 = *(const float2*)(x + (size_t)s4 * 8 + slot * 2);
                float2 u5 = *(const float2*)(x + (size_t)s5 * 8 + slot * 2);
                float2 u6 = *(const float2*)(x + (size_t)s6 * 8 + slot * 2);
                float2 u7 = *(const float2*)(x + (size_t)s7 * 8 + slot * 2);
                AX(u0) AX(u1) AX(u2) AX(u3) AX(u4) AX(u5) AX(u6) AX(u7)
            }
            for (; p < re; ++p) {
                int s = nbr[p];
                float2 u = *(const float2*)(x + (size_t)s * 8 + slot * 2);
                AX(u)
            }
#undef AX
        }
        hin[r][slot * 2]     = v.x;
        hin[r][slot * 2 + 1] = v.y;
    }
    __syncthreads();
    // MLP1 (8->128): thread = (ty: 4 rows, tx: 8 cols), bf16 into swizzled T
    int tx = t & 15, ty = t >> 4;          // ty in [0,16): rows ty*4..ty*4+4
    float w[8][8];
#pragma unroll
    for (int k = 0; k < 8; ++k) {
        float4 w0 = *(const float4*)(W1 + k * HD + tx * 8);
        float4 w1 = *(const float4*)(W1 + k * HD + tx * 8 + 4);
        w[k][0] = w0.x; w[k][1] = w0.y; w[k][2] = w0.z; w[k][3] = w0.w;
        w[k][4] = w1.x; w[k][5] = w1.y; w[k][6] = w1.z; w[k][7] = w1.w;
    }
    float4 c0 = *(const float4*)(b1 + tx * 8);
    float4 c1 = *(const float4*)(b1 + tx * 8 + 4);
    float bb[8] = {c0.x, c0.y, c0.z, c0.w, c1.x, c1.y, c1.z, c1.w};
#pragma unroll
    for (int i = 0; i < 4; ++i) {
        int r = ty * 4 + i;
        float4 a0 = *(const float4*)(&hin[r][0]);
        float4 a1 = *(const float4*)(&hin[r][4]);
        float a[8] = {a0.x, a0.y, a0.z, a0.w, a1.x, a1.y, a1.z, a1.w};
        short8 ov;
#pragma unroll
        for (int jj = 0; jj < 8; ++jj) {
            float acc = bb[jj];
#pragma unroll
            for (int k = 0; k < 8; ++k) acc += a[k] * w[k][jj];
            ov[jj] = (short)f2b(fmaxf(acc, 0.f));
        }
        *(short8*)(T + r * 128 + ((tx ^ (r & 7)) * 8)) = ov;
    }
    __syncthreads();
    gemm64(T, Wp2, b2, T, t);      // in-place, wave-private rows
    __syncthreads();
#pragma unroll
    for (int i = 0; i < 4; ++i) {
        int idx = i * 256 + t;
        int row = idx >> 4, ch = idx & 15;
        int n = n0 + row;
        if (n < nNodes) {
            short8 v = *(const short8*)(T + row * 128 + ((ch ^ (row & 7)) * 8));
            *(short8*)(out + (size_t)n * HD + ch * 8) = v;
        }
    }
    pool_tile64(T, batchl, pooled, 0, t);
}

// ---------------------------------------------------------------------------
// Fused layer MLP (layers 2,3; M=64): out = relu(relu(A@W1+b1)@W2+b2) + pool.
// STORE=0 skips the global h-store (layer 3).
// ---------------------------------------------------------------------------
template <int STORE>
__global__ __launch_bounds__(256) void fmm_k(const ushort* __restrict__ Ain,
                                             const int* __restrict__ batch,
                                             const short8* __restrict__ Wp1,
                                             const float* __restrict__ b1,
                                             const short8* __restrict__ Wp2,
                                             const float* __restrict__ b2,
                                             ushort* __restrict__ out,
                                             float* __restrict__ pooled,
                                             int coloff, int nNodes) {
    __shared__ __align__(16) ushort T[64 * 128];
    __shared__ int batchl[64];
    const int t = threadIdx.x;
    const int n0 = blockIdx.x * 64;
    if (t < 64) batchl[t] = (n0 + t < nNodes) ? batch[n0 + t] : -1;
#pragma unroll
    for (int i = 0; i < 4; ++i) {
        int idx = i * 256 + t;
        int row = idx >> 4, ch = idx & 15;
        short8 v = {0, 0, 0, 0, 0, 0, 0, 0};
        int n = n0 + row;
        if (n < nNodes) v = *(const short8*)(Ain + (size_t)n * HD + ch * 8);
        *(short8*)(T + row * 128 + ((ch ^ (row & 7)) * 8)) = v;
    }
    __syncthreads();
    gemm64(T, Wp1, b1, T, t);      // wave-private rows: no barrier needed between
    gemm64(T, Wp2, b2, T, t);      // gemm1 and gemm2
    __syncthreads();
    if constexpr (STORE) {
#pragma unroll
        for (int i = 0; i < 4; ++i) {
            int idx = i * 256 + t;
            int row = idx >> 4, ch = idx & 15;
            int n = n0 + row;
            if (n < nNodes) {
                short8 v = *(const short8*)(T + row * 128 + ((ch ^ (row & 7)) * 8));
                *(short8*)(out + (size_t)n * HD + ch * 8) = v;
            }
        }
    }
    pool_tile64(T, batchl, pooled, coloff, t);
}

// ---------------------------------------------------------------------------
// Classifier (all fp32)
// ---------------------------------------------------------------------------
__global__ __launch_bounds__(256) void cls_k(const float* __restrict__ pooled,
                                             const float* __restrict__ W1,  // 384x256
                                             const float* __restrict__ b1,
                                             const float* __restrict__ gamma,
                                             const float* __restrict__ beta,
                                             const float* __restrict__ mean,
                                             const float* __restrict__ var,
                                             const float* __restrict__ W2,  // 256x4
                                             const float* __restrict__ b2,
                                             float* __restrict__ out) {
    __shared__ float pg[384];
    __shared__ float z[256];
    int g = blockIdx.x, j = threadIdx.x;
    pg[j] = pooled[g * 384 + j];
    if (j < 128) pg[256 + j] = pooled[g * 384 + 256 + j];
    __syncthreads();
    float acc = b1[j];
    for (int k = 0; k < 384; ++k) acc += pg[k] * W1[k * 256 + j];
    acc = (acc - mean[j]) * rsqrtf(var[j] + 1e-5f) * gamma[j] + beta[j];
    z[j] = fmaxf(acc, 0.f);
    __syncthreads();
    if (j < 4) {
        float o = b2[j];
        for (int k = 0; k < 256; ++k) o += z[k] * W2[k * 4 + j];
        out[g * 4 + j] = o;
    }
}

// ---------------------------------------------------------------------------
extern "C" void kernel_launch(void* const* d_in, const int* in_sizes, int n_in,
                              void* d_out, int out_size, void* d_ws, size_t ws_size,
                              hipStream_t stream) {
    const int N = NNODES, E = NEDGES;
    const float* x     = (const float*)d_in[0];
    const int*   ei    = (const int*)d_in[1];
    const int*   batch = (const int*)d_in[2];
    const float* l1W1 = (const float*)d_in[3];
    const float* l1b1 = (const float*)d_in[4];
    const float* l1W2 = (const float*)d_in[5];
    const float* l1b2 = (const float*)d_in[6];
    const float* l2W1 = (const float*)d_in[7];
    const float* l2b1 = (const float*)d_in[8];
    const float* l2W2 = (const float*)d_in[9];
    const float* l2b2 = (const float*)d_in[10];
    const float* l3W1 = (const float*)d_in[11];
    const float* l3b1 = (const float*)d_in[12];
    const float* l3W2 = (const float*)d_in[13];
    const float* l3b2 = (const float*)d_in[14];
    const float* cW1  = (const float*)d_in[15];
    const float* cb1  = (const float*)d_in[16];
    const float* bnG  = (const float*)d_in[17];
    const float* bnB  = (const float*)d_in[18];
    const float* bnM  = (const float*)d_in[19];
    const float* bnV  = (const float*)d_in[20];
    const float* cW2  = (const float*)d_in[21];
    const float* cb2  = (const float*)d_in[22];

    const int* src = ei;
    const int* dst = ei + E;

    // ---- workspace layout ----
    char* wsp = (char*)d_ws;
    ushort* tmpb = (ushort*)wsp;  wsp += (size_t)N * HD * 2;
    ushort* h1   = (ushort*)wsp;  wsp += (size_t)N * HD * 2;
    ushort* h2   = (ushort*)wsp;  wsp += (size_t)N * HD * 2;
    float* pooled = (float*)wsp;  wsp += (size_t)64 * 384 * 4;
    ushort* wp    = (ushort*)wsp; wsp += (size_t)5 * 16384 * 2;
    int* count    = (int*)wsp;    wsp += (size_t)N * 4;
    int* row_tmp  = (int*)wsp;    wsp += (size_t)N * 4;
    int* blocksum = (int*)wsp;    wsp += 256 * 4;
    int* row_start = (int*)wsp;   wsp += (size_t)(N + 1) * 4;
    int* cur       = (int*)wsp;   wsp += (size_t)N * 4;
    ushort* nbr    = (ushort*)wsp; wsp += (size_t)E * 2;

    const int nB = (N + 255) / 256;              // 196
    wpinit_k<<<dim3(8, 5), 256, 0, stream>>>(l1W2, l2W1, l2W2, l3W1, l3W2,
                                             wp, count, pooled);
    phist_k<<<2048, 256, 0, stream>>>(dst, count, E);
    scan1_k<<<nB, 256, 0, stream>>>(count, row_tmp, blocksum, N);
    scan23_k<<<nB, 256, 0, stream>>>(count, row_tmp, blocksum, nB, row_start, cur, N, E);
    pscatter_k<<<2048, 256, 0, stream>>>(src, dst, cur, nbr, E);

    const short8* Wp0 = (const short8*)(wp);
    const short8* Wp1 = (const short8*)(wp + 16384);
    const short8* Wp2 = (const short8*)(wp + 2 * 16384);
    const short8* Wp3 = (const short8*)(wp + 3 * 16384);
    const short8* Wp4 = (const short8*)(wp + 4 * 16384);

    const int mb64 = (N + 63) / 64;              // 782 tiles
    const int ab = ((N + 1) / 2 * 64) / 256;     // 6250 blocks
    // layer 1 (gather + MLP1 + GEMM2 + pool fused)
    fl1_k<<<mb64, 256, 0, stream>>>(x, batch, row_start, nbr, l1W1, l1b1, Wp0, l1b2,
                                    h1, pooled, N);
    // layer 2
    aggb_k<<<ab, 256, 0, stream>>>(h1, row_start, nbr, tmpb, N);
    fmm_k<1><<<mb64, 256, 0, stream>>>(tmpb, batch, Wp1, l2b1, Wp2, l2b2, h2,
                                       pooled, 128, N);
    // layer 3 (no h3 store)
    aggb_k<<<ab, 256, 0, stream>>>(h2, row_start, nbr, tmpb, N);
    fmm_k<0><<<mb64, 256, 0, stream>>>(tmpb, batch, Wp3, l3b1, Wp4, l3b2, nullptr,
                                       pooled, 256, N);
    // classifier
    cls_k<<<NGRAPH, 256, 0, stream>>>(pooled, cW1, cb1, bnG, bnB, bnM, bnV, cW2, cb2,
                                      (float*)d_out);
}

// Round 14
// 213.486 us; speedup vs baseline: 2.3124x; 1.0353x over previous
//
#include <hip/hip_runtime.h>
#include <hip/hip_bf16.h>

#define NNODES 50000
#define NEDGES 640000
#define NGRAPH 64
#define HD     128
#define NPART  8
#define PRANGE (NNODES / NPART)   // 6250 (dst-range partition for CSR build)

typedef __attribute__((ext_vector_type(8))) short short8;
typedef __attribute__((ext_vector_type(4))) float f32x4;

__device__ __forceinline__ float uf(uint u) { return __uint_as_float(u); }
// fp32 -> bf16 round-to-nearest-even
__device__ __forceinline__ ushort f2b(float f) {
    uint u = __float_as_uint(f);
    return (ushort)((u + 0x7fffu + ((u >> 16) & 1u)) >> 16);
}

// ---------------------------------------------------------------------------
// wpinit: pack 5 fp32 128x128 weights into bf16 MFMA B-fragment order,
// AND zero count[] + pooled[].
// ---------------------------------------------------------------------------
__global__ __launch_bounds__(256) void wpinit_k(const float* __restrict__ W0,
                                                const float* __restrict__ W1,
                                                const float* __restrict__ W2,
                                                const float* __restrict__ W3,
                                                const float* __restrict__ W4,
                                                ushort* __restrict__ Wp,
                                                int* __restrict__ count,
                                                float* __restrict__ pooled) {
    int which = blockIdx.y;
    const float* W = (which == 0) ? W0 : (which == 1) ? W1 : (which == 2) ? W2
                   : (which == 3) ? W3 : W4;
    ushort* dst = Wp + (size_t)which * 16384;
    int idx = blockIdx.x * 256 + threadIdx.x;   // 0..2047
    int l  = idx & 63;
    int kt = (idx >> 6) & 3;
    int nt = idx >> 8;
    int krow = kt * 32 + (l >> 4) * 8;
    int col  = nt * 16 + (l & 15);
    short8 v;
#pragma unroll
    for (int j = 0; j < 8; ++j) v[j] = (short)f2b(W[(size_t)(krow + j) * HD + col]);
    *(short8*)(dst + ((size_t)(nt * 4 + kt) * 64 + l) * 8) = v;
    int fid = (blockIdx.y * 8 + blockIdx.x) * 256 + threadIdx.x;
    for (int i = fid; i < NNODES; i += 10240) count[i] = 0;
    for (int i = fid; i < NGRAPH * 384; i += 10240) pooled[i] = 0.f;
}

// ---------------------------------------------------------------------------
// CSR build (round-8 structure: separate kernels, XCD dst-range partitioned)
// ---------------------------------------------------------------------------
__global__ __launch_bounds__(256) void phist_k(const int* __restrict__ dst,
                                               int* __restrict__ count, int E) {
    int p = blockIdx.x & 7;
    int q = blockIdx.x >> 3;
    int lo = p * PRANGE, hi = lo + PRANGE;
    for (int e = q * 256 + threadIdx.x; e < E; e += 256 * 256) {
        int d = dst[e];
        if (d >= lo && d < hi) atomicAdd(&count[d], 1);
    }
}

__global__ __launch_bounds__(256) void scan1_k(const int* __restrict__ count,
                                               int* __restrict__ row_tmp,
                                               int* __restrict__ blocksum, int N) {
    __shared__ int s[256];
    int t = threadIdx.x;
    int i = blockIdx.x * 256 + t;
    int v = (i < N) ? count[i] : 0;
    s[t] = v;
    __syncthreads();
    for (int off = 1; off < 256; off <<= 1) {
        int nv = s[t];
        if (t >= off) nv += s[t - off];
        __syncthreads();
        s[t] = nv;
        __syncthreads();
    }
    if (i < N) row_tmp[i] = s[t];
    if (t == 255) blocksum[blockIdx.x] = s[255];
}

__global__ __launch_bounds__(256) void scan23_k(const int* __restrict__ count,
                                                const int* __restrict__ row_tmp,
                                                const int* __restrict__ blocksum,
                                                int nB,
                                                int* __restrict__ row_start,
                                                int* __restrict__ cur, int N, int E) {
    __shared__ int s[256];
    int t = threadIdx.x;
    s[t] = (t < nB) ? blocksum[t] : 0;
    __syncthreads();
    for (int off = 1; off < 256; off <<= 1) {
        int nv = s[t];
        if (t >= off) nv += s[t - off];
        __syncthreads();
        s[t] = nv;
        __syncthreads();
    }
    int bid = blockIdx.x;
    int boff = (bid == 0) ? 0 : s[bid - 1];
    int i = bid * 256 + t;
    if (i < N) {
        int excl = row_tmp[i] - count[i] + boff;
        row_start[i] = excl;
        cur[i] = excl;
    }
    if (i == N) row_start[N] = E;
}

__global__ __launch_bounds__(256) void pscatter_k(const int* __restrict__ src,
                                                  const int* __restrict__ dst,
                                                  int* __restrict__ cur,
                                                  ushort* __restrict__ nbr, int E) {
    int p = blockIdx.x & 7;
    int q = blockIdx.x >> 3;
    int lo = p * PRANGE, hi = lo + PRANGE;
    for (int e = q * 256 + threadIdx.x; e < E; e += 256 * 256) {
        int d = dst[e];
        if (d >= lo && d < hi) {
            int pos = atomicAdd(&cur[d], 1);
            nbr[pos] = (ushort)src[e];
        }
    }
}

// ---------------------------------------------------------------------------
// bf16 aggregation: out[n] = h[n] + sum h[s]   (fp32 accumulate)
// 4 nodes per wave, 16 lanes x uint4 (16B) per row: same 256B coalesced
// footprint as round-8's 32x8B, but HALF the load instructions per row and
// 2x rows in flight per wave (issue-rate fix). Unroll x4 (16 loads in
// flight per 16-lane group).
// ---------------------------------------------------------------------------
__global__ __launch_bounds__(256) void aggb_k(const ushort* __restrict__ h,
                                              const int* __restrict__ row_start,
                                              const ushort* __restrict__ nbr,
                                              ushort* __restrict__ out, int nNodes) {
    int gw   = (blockIdx.x * 256 + threadIdx.x) >> 6;
    int lane = threadIdx.x & 63;
    int node = gw * 4 + (lane >> 4);
    int sub  = lane & 15;                       // uint4 slot within the 256B row
    if (node >= nNodes) return;
    const uint4* hp = (const uint4*)h;
    uint4 u = hp[(size_t)node * 16 + sub];
    float f0 = uf(u.x << 16), f1 = uf(u.x & 0xffff0000u);
    float f2v = uf(u.y << 16), f3 = uf(u.y & 0xffff0000u);
    float f4 = uf(u.z << 16), f5 = uf(u.z & 0xffff0000u);
    float f6 = uf(u.w << 16), f7 = uf(u.w & 0xffff0000u);
    int rs = row_start[node], re = row_start[node + 1];
    int p = rs;
#define ACC8(vv) { f0 += uf(vv.x << 16); f1 += uf(vv.x & 0xffff0000u); \
                   f2v += uf(vv.y << 16); f3 += uf(vv.y & 0xffff0000u); \
                   f4 += uf(vv.z << 16); f5 += uf(vv.z & 0xffff0000u); \
                   f6 += uf(vv.w << 16); f7 += uf(vv.w & 0xffff0000u); }
    for (; p + 4 <= re; p += 4) {
        int s0 = nbr[p], s1 = nbr[p + 1], s2 = nbr[p + 2], s3 = nbr[p + 3];
        uint4 v0 = hp[(size_t)s0 * 16 + sub];
        uint4 v1 = hp[(size_t)s1 * 16 + sub];
        uint4 v2 = hp[(size_t)s2 * 16 + sub];
        uint4 v3 = hp[(size_t)s3 * 16 + sub];
        ACC8(v0) ACC8(v1) ACC8(v2) ACC8(v3)
    }
    for (; p < re; ++p) {
        int s = nbr[p];
        uint4 v = hp[(size_t)s * 16 + sub];
        ACC8(v)
    }
#undef ACC8
    uint4 o;
    o.x = (uint)f2b(f0) | ((uint)f2b(f1) << 16);
    o.y = (uint)f2b(f2v) | ((uint)f2b(f3) << 16);
    o.z = (uint)f2b(f4) | ((uint)f2b(f5) << 16);
    o.w = (uint)f2b(f6) | ((uint)f2b(f7) << 16);
    ((uint4*)out)[(size_t)node * 16 + sub] = o;
}

// ---------------------------------------------------------------------------
// 128x128 bf16 MFMA GEMM step on an LDS tile (round-8 version).
// Wave-private rows [32w, 32w+32). D = bf16(relu(A @ Wp + bias)).
// ---------------------------------------------------------------------------
__device__ __forceinline__ void gemm128(const ushort* __restrict__ A,
                                        const short8* __restrict__ Wp,
                                        const float* __restrict__ bias,
                                        ushort* __restrict__ D, int tid) {
    const int l = tid & 63, w = tid >> 6;
    const int lr = l & 15, lg = l >> 4;
    const int wbase = w * 32;
    const int sw = lr & 7;
    f32x4 acc[2][8];
    const f32x4 z4 = {0.f, 0.f, 0.f, 0.f};
#pragma unroll
    for (int m = 0; m < 2; ++m)
#pragma unroll
        for (int n = 0; n < 8; ++n) acc[m][n] = z4;
#pragma unroll
    for (int kt = 0; kt < 4; ++kt) {
        const int pch = ((kt * 4 + lg) ^ sw) * 8;
        short8 a0 = *(const short8*)(A + (wbase + lr) * 128 + pch);
        short8 a1 = *(const short8*)(A + (wbase + 16 + lr) * 128 + pch);
#pragma unroll
        for (int n = 0; n < 8; ++n) {
            short8 b = Wp[(n * 4 + kt) * 64 + l];
            acc[0][n] = __builtin_amdgcn_mfma_f32_16x16x32_bf16(a0, b, acc[0][n], 0, 0, 0);
            acc[1][n] = __builtin_amdgcn_mfma_f32_16x16x32_bf16(a1, b, acc[1][n], 0, 0, 0);
        }
    }
#pragma unroll
    for (int n = 0; n < 8; ++n) {
        const int col = n * 16 + lr;
        const float bb = bias[col];
        const int cch = col >> 3, cof = col & 7;
#pragma unroll
        for (int m = 0; m < 2; ++m) {
#pragma unroll
            for (int r = 0; r < 4; ++r) {
                int row = wbase + m * 16 + lg * 4 + r;
                float t = fmaxf(acc[m][n][r] + bb, 0.f);
                D[row * 128 + ((cch ^ (row & 7)) * 8) + cof] = f2b(t);
            }
        }
    }
}

// Segmented pool of the LDS tile into pooled[g*384 + coloff + col].
__device__ __forceinline__ void pool_tile(const ushort* __restrict__ T,
                                          const int* __restrict__ batchl,
                                          float* __restrict__ pooled,
                                          int coloff, int tid) {
    int col = tid & 127, half = tid >> 7;
    int cch = col >> 3, cof = col & 7;
    float pacc = 0.f;
    int curg = -1;
    for (int r = half * 64; r < half * 64 + 64; ++r) {
        int g = batchl[r];
        if (g != curg) {
            if (curg >= 0) atomicAdd(&pooled[curg * 384 + coloff + col], pacc);
            curg = g;
            pacc = 0.f;
        }
        if (g >= 0) pacc += uf((uint)T[r * 128 + ((cch ^ (r & 7)) * 8) + cof] << 16);
    }
    if (curg >= 0) atomicAdd(&pooled[curg * 384 + coloff + col], pacc);
}

// ---------------------------------------------------------------------------
// Fused layer 1 (round-8): h1 = relu(relu((x+agg(x))@W1+b1)@W2+b2) + pool
// ---------------------------------------------------------------------------
__global__ __launch_bounds__(256) void fl1_k(const float* __restrict__ x,
                                             const int* __restrict__ batch,
                                             const int* __restrict__ row_start,
                                             const ushort* __restrict__ nbr,
                                             const float* __restrict__ W1, // 8x128
                                             const float* __restrict__ b1,
                                             const short8* __restrict__ Wp2,
                                             const float* __restrict__ b2,
                                             ushort* __restrict__ out,
                                             float* __restrict__ pooled, int nNodes) {
    __shared__ float hin[128][8];
    __shared__ __align__(16) ushort T[128 * 128];
    __shared__ int batchl[128];
    int t = threadIdx.x;
    int n0 = blockIdx.x * 128;
    if (t < 128) batchl[t] = (n0 + t < nNodes) ? batch[n0 + t] : -1;
    {   // gather-sum staging: 2 threads per row, unroll x8
        int r = t >> 1;
        int half = t & 1;
        int n = n0 + r;
        float4 v = make_float4(0.f, 0.f, 0.f, 0.f);
        if (n < nNodes) {
            v = *(const float4*)(x + (size_t)n * 8 + half * 4);
            int rs = row_start[n], re = row_start[n + 1];
            int p = rs;
#define AX(u) { v.x += u.x; v.y += u.y; v.z += u.z; v.w += u.w; }
            for (; p + 8 <= re; p += 8) {
                int s0 = nbr[p],     s1 = nbr[p + 1], s2 = nbr[p + 2], s3 = nbr[p + 3];
                int s4 = nbr[p + 4], s5 = nbr[p + 5], s6 = nbr[p + 6], s7 = nbr[p + 7];
                float4 u0 = *(const float4*)(x + (size_t)s0 * 8 + half * 4);
                float4 u1 = *(const float4*)(x + (size_t)s1 * 8 + half * 4);
                float4 u2 = *(const float4*)(x + (size_t)s2 * 8 + half * 4);
                float4 u3 = *(const float4*)(x + (size_t)s3 * 8 + half * 4);
                float4 u4 = *(const float4*)(x + (size_t)s4 * 8 + half * 4);
                float4 u5 = *(const float4*)(x + (size_t)s5 * 8 + half * 4);
                float4 u6 = *(const float4*)(x + (size_t)s6 * 8 + half * 4);
                float4 u7 = *(const float4*)(x + (size_t)s7 * 8 + half * 4);
                AX(u0) AX(u1) AX(u2) AX(u3) AX(u4) AX(u5) AX(u6) AX(u7)
            }
            for (; p < re; ++p) {
                int s = nbr[p];
                float4 u = *(const float4*)(x + (size_t)s * 8 + half * 4);
                AX(u)
            }
#undef AX
        }
        *(float4*)(&hin[r][half * 4]) = v;
    }
    __syncthreads();
    // MLP1 (8->128), bf16 result into swizzled T
    int tx = t & 15, ty = t >> 4;
    float w[8][8];
#pragma unroll
    for (int k = 0; k < 8; ++k) {
        float4 w0 = *(const float4*)(W1 + k * HD + tx * 8);
        float4 w1 = *(const float4*)(W1 + k * HD + tx * 8 + 4);
        w[k][0] = w0.x; w[k][1] = w0.y; w[k][2] = w0.z; w[k][3] = w0.w;
        w[k][4] = w1.x; w[k][5] = w1.y; w[k][6] = w1.z; w[k][7] = w1.w;
    }
    float4 c0 = *(const float4*)(b1 + tx * 8);
    float4 c1 = *(const float4*)(b1 + tx * 8 + 4);
    float bb[8] = {c0.x, c0.y, c0.z, c0.w, c1.x, c1.y, c1.z, c1.w};
#pragma unroll
    for (int i = 0; i < 8; ++i) {
        int r = ty * 8 + i;
        float4 a0 = *(const float4*)(&hin[r][0]);
        float4 a1 = *(const float4*)(&hin[r][4]);
        float a[8] = {a0.x, a0.y, a0.z, a0.w, a1.x, a1.y, a1.z, a1.w};
        short8 ov;
#pragma unroll
        for (int jj = 0; jj < 8; ++jj) {
            float acc = bb[jj];
#pragma unroll
            for (int k = 0; k < 8; ++k) acc += a[k] * w[k][jj];
            ov[jj] = (short)f2b(fmaxf(acc, 0.f));
        }
        *(short8*)(T + r * 128 + ((tx ^ (r & 7)) * 8)) = ov;
    }
    __syncthreads();
    gemm128(T, Wp2, b2, T, t);     // in-place, wave-private rows
    __syncthreads();
#pragma unroll
    for (int i = 0; i < 8; ++i) {
        int idx = i * 256 + t;
        int row = idx >> 4, ch = idx & 15;
        int n = n0 + row;
        if (n < nNodes) {
            short8 v = *(const short8*)(T + row * 128 + ((ch ^ (row & 7)) * 8));
            *(short8*)(out + (size_t)n * HD + ch * 8) = v;
        }
    }
    pool_tile(T, batchl, pooled, 0, t);
}

// ---------------------------------------------------------------------------
// Fused layer MLP (layers 2,3; round-8): out = relu(relu(A@W1+b1)@W2+b2) + pool.
// STORE=0 skips the global h-store (layer 3).
// ---------------------------------------------------------------------------
template <int STORE>
__global__ __launch_bounds__(256) void fmm_k(const ushort* __restrict__ Ain,
                                             const int* __restrict__ batch,
                                             const short8* __restrict__ Wp1,
                                             const float* __restrict__ b1,
                                             const short8* __restrict__ Wp2,
                                             const float* __restrict__ b2,
                                             ushort* __restrict__ out,
                                             float* __restrict__ pooled,
                                             int coloff, int nNodes) {
    __shared__ __align__(16) ushort T[128 * 128];
    __shared__ int batchl[128];
    const int t = threadIdx.x;
    const int n0 = blockIdx.x * 128;
    if (t < 128) batchl[t] = (n0 + t < nNodes) ? batch[n0 + t] : -1;
#pragma unroll
    for (int i = 0; i < 8; ++i) {
        int idx = i * 256 + t;
        int row = idx >> 4, ch = idx & 15;
        short8 v = {0, 0, 0, 0, 0, 0, 0, 0};
        int n = n0 + row;
        if (n < nNodes) v = *(const short8*)(Ain + (size_t)n * HD + ch * 8);
        *(short8*)(T + row * 128 + ((ch ^ (row & 7)) * 8)) = v;
    }
    __syncthreads();
    gemm128(T, Wp1, b1, T, t);
    __syncthreads();
    gemm128(T, Wp2, b2, T, t);
    __syncthreads();
    if constexpr (STORE) {
#pragma unroll
        for (int i = 0; i < 8; ++i) {
            int idx = i * 256 + t;
            int row = idx >> 4, ch = idx & 15;
            int n = n0 + row;
            if (n < nNodes) {
                short8 v = *(const short8*)(T + row * 128 + ((ch ^ (row & 7)) * 8));
                *(short8*)(out + (size_t)n * HD + ch * 8) = v;
            }
        }
    }
    pool_tile(T, batchl, pooled, coloff, t);
}

// ---------------------------------------------------------------------------
// Classifier (all fp32)
// ---------------------------------------------------------------------------
__global__ __launch_bounds__(256) void cls_k(const float* __restrict__ pooled,
                                             const float* __restrict__ W1,  // 384x256
                                             const float* __restrict__ b1,
                                             const float* __restrict__ gamma,
                                             const float* __restrict__ beta,
                                             const float* __restrict__ mean,
                                             const float* __restrict__ var,
                                             const float* __restrict__ W2,  // 256x4
                                             const float* __restrict__ b2,
                                             float* __restrict__ out) {
    __shared__ float pg[384];
    __shared__ float z[256];
    int g = blockIdx.x, j = threadIdx.x;
    pg[j] = pooled[g * 384 + j];
    if (j < 128) pg[256 + j] = pooled[g * 384 + 256 + j];
    __syncthreads();
    float acc = b1[j];
    for (int k = 0; k < 384; ++k) acc += pg[k] * W1[k * 256 + j];
    acc = (acc - mean[j]) * rsqrtf(var[j] + 1e-5f) * gamma[j] + beta[j];
    z[j] = fmaxf(acc, 0.f);
    __syncthreads();
    if (j < 4) {
        float o = b2[j];
        for (int k = 0; k < 256; ++k) o += z[k] * W2[k * 4 + j];
        out[g * 4 + j] = o;
    }
}

// ---------------------------------------------------------------------------
extern "C" void kernel_launch(void* const* d_in, const int* in_sizes, int n_in,
                              void* d_out, int out_size, void* d_ws, size_t ws_size,
                              hipStream_t stream) {
    const int N = NNODES, E = NEDGES;
    const float* x     = (const float*)d_in[0];
    const int*   ei    = (const int*)d_in[1];
    const int*   batch = (const int*)d_in[2];
    const float* l1W1 = (const float*)d_in[3];
    const float* l1b1 = (const float*)d_in[4];
    const float* l1W2 = (const float*)d_in[5];
    const float* l1b2 = (const float*)d_in[6];
    const float* l2W1 = (const float*)d_in[7];
    const float* l2b1 = (const float*)d_in[8];
    const float* l2W2 = (const float*)d_in[9];
    const float* l2b2 = (const float*)d_in[10];
    const float* l3W1 = (const float*)d_in[11];
    const float* l3b1 = (const float*)d_in[12];
    const float* l3W2 = (const float*)d_in[13];
    const float* l3b2 = (const float*)d_in[14];
    const float* cW1  = (const float*)d_in[15];
    const float* cb1  = (const float*)d_in[16];
    const float* bnG  = (const float*)d_in[17];
    const float* bnB  = (const float*)d_in[18];
    const float* bnM  = (const float*)d_in[19];
    const float* bnV  = (const float*)d_in[20];
    const float* cW2  = (const float*)d_in[21];
    const float* cb2  = (const float*)d_in[22];

    const int* src = ei;
    const int* dst = ei + E;

    // ---- workspace layout ----
    char* wsp = (char*)d_ws;
    ushort* tmpb = (ushort*)wsp;  wsp += (size_t)N * HD * 2;
    ushort* h1   = (ushort*)wsp;  wsp += (size_t)N * HD * 2;
    ushort* h2   = (ushort*)wsp;  wsp += (size_t)N * HD * 2;
    float* pooled = (float*)wsp;  wsp += (size_t)64 * 384 * 4;
    ushort* wp    = (ushort*)wsp; wsp += (size_t)5 * 16384 * 2;
    int* count    = (int*)wsp;    wsp += (size_t)N * 4;
    int* row_tmp  = (int*)wsp;    wsp += (size_t)N * 4;
    int* blocksum = (int*)wsp;    wsp += 256 * 4;
    int* row_start = (int*)wsp;   wsp += (size_t)(N + 1) * 4;
    int* cur       = (int*)wsp;   wsp += (size_t)N * 4;
    ushort* nbr    = (ushort*)wsp; wsp += (size_t)E * 2;

    const int nB = (N + 255) / 256;              // 196
    wpinit_k<<<dim3(8, 5), 256, 0, stream>>>(l1W2, l2W1, l2W2, l3W1, l3W2,
                                             wp, count, pooled);
    phist_k<<<2048, 256, 0, stream>>>(dst, count, E);
    scan1_k<<<nB, 256, 0, stream>>>(count, row_tmp, blocksum, N);
    scan23_k<<<nB, 256, 0, stream>>>(count, row_tmp, blocksum, nB, row_start, cur, N, E);
    pscatter_k<<<2048, 256, 0, stream>>>(src, dst, cur, nbr, E);

    const short8* Wp0 = (const short8*)(wp);
    const short8* Wp1 = (const short8*)(wp + 16384);
    const short8* Wp2 = (const short8*)(wp + 2 * 16384);
    const short8* Wp3 = (const short8*)(wp + 3 * 16384);
    const short8* Wp4 = (const short8*)(wp + 4 * 16384);

    const int mb = (N + 127) / 128;              // 391 tiles
    const int ab = (N + 15) / 16;                // 3125 blocks (4 nodes/wave)
    // layer 1 (gather + MLP1 + GEMM2 + pool fused)
    fl1_k<<<mb, 256, 0, stream>>>(x, batch, row_start, nbr, l1W1, l1b1, Wp0, l1b2,
                                  h1, pooled, N);
    // layer 2
    aggb_k<<<ab, 256, 0, stream>>>(h1, row_start, nbr, tmpb, N);
    fmm_k<1><<<mb, 256, 0, stream>>>(tmpb, batch, Wp1, l2b1, Wp2, l2b2, h2,
                                     pooled, 128, N);
    // layer 3 (no h3 store)
    aggb_k<<<ab, 256, 0, stream>>>(h2, row_start, nbr, tmpb, N);
    fmm_k<0><<<mb, 256, 0, stream>>>(tmpb, batch, Wp3, l3b1, Wp4, l3b2, nullptr,
                                     pooled, 256, N);
    // classifier
    cls_k<<<NGRAPH, 256, 0, stream>>>(pooled, cW1, cb1, bnG, bnB, bnM, bnV, cW2, cb2,
                                      (float*)d_out);
}